// Round 1
// baseline (677.438 us; speedup 1.0000x reference)
//
#include <hip/hip_runtime.h>
#include <hip/hip_bf16.h>
#include <math.h>

typedef __bf16 bf16;
typedef __bf16 bf16x8 __attribute__((ext_vector_type(8)));
typedef float  f32x4  __attribute__((ext_vector_type(4)));

#define MFMA(a,b,c) __builtin_amdgcn_mfma_f32_16x16x32_bf16(a,b,c,0,0,0)

__device__ __forceinline__ void gload16(const void* g, void* l) {
  __builtin_amdgcn_global_load_lds((__attribute__((address_space(1))) void*)(g),
                                   (__attribute__((address_space(3))) void*)(l), 16, 0, 0);
}

// ---------------- fp32 -> bf16 cast (vectorized, G13) ----------------
__global__ void cast_kernel(const float* __restrict__ in, bf16* __restrict__ out, int n8) {
  int i = blockIdx.x * 256 + threadIdx.x;
  if (i >= n8) return;
  const float4* p = (const float4*)in;
  float4 a = p[2*i], b = p[2*i+1];
  bf16x8 v;
  v[0]=(bf16)a.x; v[1]=(bf16)a.y; v[2]=(bf16)a.z; v[3]=(bf16)a.w;
  v[4]=(bf16)b.x; v[5]=(bf16)b.y; v[6]=(bf16)b.z; v[7]=(bf16)b.w;
  *(bf16x8*)(out + (size_t)8*i) = v;
}

// ---------------- m97-style 128x128 GEMM, C = A @ B^T, bf16 in / fp32 acc ----
// A: [M][K] bf16, B: [N][K] bf16.  EPI: 0=write bf16; 1=+add -> f32 & bf16;
// 2=+bias, exact GELU -> bf16; 3=+bias+add -> f32 (final output)
template<int EPI>
__global__ __launch_bounds__(256) void gemm_bt(
    const bf16* __restrict__ A, const bf16* __restrict__ B,
    float* __restrict__ outf, bf16* __restrict__ outb,
    const float* __restrict__ add, const float* __restrict__ bias,
    int M, int N, int K)
{
  __shared__ bf16 As[128*32];
  __shared__ bf16 Bs[128*32];
  const int tid = threadIdx.x;
  const int w = tid >> 6, l = tid & 63, lg = l >> 4, li = l & 15;
  const int m0 = blockIdx.y << 7, n0 = blockIdx.x << 7;
  const int wm = (w >> 1) << 6, wn = (w & 1) << 6;

  const bf16* ga = A + (size_t)(m0 + (tid >> 2)) * K + ((tid & 3) << 3);
  const bf16* gb = B + (size_t)(n0 + (tid >> 2)) * K + ((tid & 3) << 3);
  const size_t half = (size_t)64 * K;

  f32x4 acc[4][4] = {};

  for (int k0 = 0; k0 < K; k0 += 32) {
    __syncthreads();
    // global -> LDS direct, 16B/lane; LDS dest linear (wave-uniform base + lane*16)
    gload16(ga + k0,        As + (w << 9));
    gload16(ga + k0 + half, As + 2048 + (w << 9));
    gload16(gb + k0,        Bs + (w << 9));
    gload16(gb + k0 + half, Bs + 2048 + (w << 9));
    __syncthreads();

    bf16x8 af[4], bfv[4];
    #pragma unroll
    for (int i = 0; i < 4; i++)
      af[i] = *(const bf16x8*)(As + (size_t)(wm + (i << 4) + li) * 32 + (lg << 3));
    #pragma unroll
    for (int i = 0; i < 4; i++)
      bfv[i] = *(const bf16x8*)(Bs + (size_t)(wn + (i << 4) + li) * 32 + (lg << 3));
    #pragma unroll
    for (int mi = 0; mi < 4; mi++)
      #pragma unroll
      for (int ni = 0; ni < 4; ni++)
        acc[mi][ni] = MFMA(af[mi], bfv[ni], acc[mi][ni]);
  }

  #pragma unroll
  for (int mi = 0; mi < 4; mi++) {
    const int row = m0 + wm + (mi << 4) + (lg << 2);
    #pragma unroll
    for (int ni = 0; ni < 4; ni++) {
      const int col = n0 + wn + (ni << 4) + li;
      #pragma unroll
      for (int r = 0; r < 4; r++) {
        const size_t idx = (size_t)(row + r) * N + col;
        float v = acc[mi][ni][r];
        if (EPI == 0) {
          outb[idx] = (bf16)v;
        } else if (EPI == 1) {
          float s = v + add[idx];
          outf[idx] = s; outb[idx] = (bf16)s;
        } else if (EPI == 2) {
          float s = v + bias[col];
          s = 0.5f * s * (1.0f + erff(s * 0.70710678118654752f));  // exact GELU
          outb[idx] = (bf16)s;
        } else {
          outf[idx] = v + bias[col] + add[idx];
        }
      }
    }
  }
}

// ---------------- causal flash attention ------------------------------------
// qkv: [B*S][3072] bf16 (cols: 0..1023 Q, 1024..2047 K, 2048..3071 V; per head h
// sub-cols h*64..h*64+63).  z: [B*S][1024] bf16 (col = head*64 + d).
// Block = 256 thr = 4 waves; block owns (b, head, 64 q rows); wave owns 16 rows.
__global__ __launch_bounds__(256) void attn_kernel(const bf16* __restrict__ qkv,
                                                   bf16* __restrict__ z)
{
  __shared__ bf16 Ksh[32*64];   // chunk-XOR-swizzled: row p, slot c holds chunk c^(p&7)
  __shared__ bf16 VS[32*64];    // [kg=kk>>3][f(dd)][j=kk&7], f(dd)=dd^((dd>>3)&7)
  __shared__ bf16 Pl[4*16*32];  // per-wave P tile, chunk-XOR-swizzled

  const int tid = threadIdx.x;
  const int w = tid >> 6, l = tid & 63, lg = l >> 4, li = l & 15;
  const int qt = blockIdx.x & 31, bh = blockIdx.x >> 5;
  const int h = bh & 15, b = bh >> 4;
  const int q0 = qt << 6;
  const int qb = q0 + (w << 4);
  const size_t tb = (size_t)b * 2048;

  // Q fragments held in registers (A-operand: row=li, k-chunk=lg)
  const bf16* Qp = qkv + (tb + qb + li) * 3072 + (h << 6);
  const bf16x8 qa0 = *(const bf16x8*)(Qp + (lg << 3));
  const bf16x8 qa1 = *(const bf16x8*)(Qp + 32 + (lg << 3));

  f32x4 zacc[4] = {};
  float mR[4] = {-1e30f, -1e30f, -1e30f, -1e30f};
  float lS[4] = {0.f, 0.f, 0.f, 0.f};

  // staging mapping: thread covers tile-row sp, 16B chunk sc
  const int sp = tid >> 3, sc = tid & 7;
  // K global source pre-swizzled (chunk ^= sp&7) so linear LDS dest + swizzled read agree
  const bf16* Kg = qkv + (tb + sp) * 3072 + 1024 + (h << 6) + ((sc ^ (sp & 7)) << 3);
  const bf16* Vg = qkv + (tb + sp) * 3072 + 2048 + (h << 6) + (sc << 3);
  const int d0 = sc << 3;
  const int vkg = (sp >> 3) << 9;   // kg*512
  const int vj  = sp & 7;

  const int nkt = (q0 + 64) >> 5;   // causal: only key tiles with p < q0+64
  for (int kt = 0; kt < nkt; ++kt) {
    const size_t koff = (size_t)(kt << 5) * 3072;
    __syncthreads();
    gload16(Kg + koff, Ksh + (w << 9));          // K tile 4KB, 1 load/thread
    {
      bf16x8 vv = *(const bf16x8*)(Vg + koff);   // V reg-stage + scatter to subtile layout
      #pragma unroll
      for (int j2 = 0; j2 < 8; j2++) {
        int dd = d0 + j2;
        int fdd = dd ^ ((dd >> 3) & 7);          // bank-spreading bijection
        VS[vkg + (fdd << 3) + vj] = vv[j2];
      }
    }
    __syncthreads();

    // S = Q K^T  (two 16-wide p sub-tiles, K=32 over d twice)
    f32x4 s0 = {0,0,0,0}, s1 = {0,0,0,0};
    {
      const int x0 = li & 7, x1 = (li + 16) & 7;
      bf16x8 kb;
      kb = *(const bf16x8*)((const char*)Ksh + li*128        + ((lg       ^ x0) << 4)); s0 = MFMA(qa0, kb, s0);
      kb = *(const bf16x8*)((const char*)Ksh + li*128        + (((lg + 4) ^ x0) << 4)); s0 = MFMA(qa1, kb, s0);
      kb = *(const bf16x8*)((const char*)Ksh + (li+16)*128   + ((lg       ^ x1) << 4)); s1 = MFMA(qa0, kb, s1);
      kb = *(const bf16x8*)((const char*)Ksh + (li+16)*128   + (((lg + 4) ^ x1) << 4)); s1 = MFMA(qa1, kb, s1);
    }

    // online softmax (rows live in (lg, r); reduce over 16 lanes of the group)
    const int pb = kt << 5;
    const int pg0 = pb + li, pg1 = pb + 16 + li;
    const int qg = qb + (lg << 2);
    float corr[4];
    #pragma unroll
    for (int r = 0; r < 4; r++) {
      float v0 = s0[r] * 0.125f, v1 = s1[r] * 0.125f;   // 1/sqrt(64)
      if (pg0 > qg + r) v0 = -1e30f;                    // causal mask
      if (pg1 > qg + r) v1 = -1e30f;
      float mx = fmaxf(v0, v1);
      mx = fmaxf(mx, __shfl_xor(mx, 1));
      mx = fmaxf(mx, __shfl_xor(mx, 2));
      mx = fmaxf(mx, __shfl_xor(mx, 4));
      mx = fmaxf(mx, __shfl_xor(mx, 8));
      float mn = fmaxf(mR[r], mx);
      float c  = __expf(mR[r] - mn);
      float p0 = __expf(v0 - mn);
      float p1 = __expf(v1 - mn);
      float sm = p0 + p1;
      sm += __shfl_xor(sm, 1);
      sm += __shfl_xor(sm, 2);
      sm += __shfl_xor(sm, 4);
      sm += __shfl_xor(sm, 8);
      lS[r] = lS[r] * c + sm;
      mR[r] = mn; corr[r] = c;
      s0[r] = p0; s1[r] = p1;
    }
    #pragma unroll
    for (int d = 0; d < 4; d++) {
      zacc[d][0] *= corr[0]; zacc[d][1] *= corr[1];
      zacc[d][2] *= corr[2]; zacc[d][3] *= corr[3];
    }

    // P -> wave-private LDS (swizzled), read back as MFMA A-operand
    char* pw = (char*)Pl + (w << 10);
    #pragma unroll
    for (int r = 0; r < 4; r++) {
      int q_ = (lg << 2) + r;
      int sw = ((q_ ^ (q_ >> 2)) & 3) << 4;
      *(bf16*)(pw + q_*64 + ((li << 1) ^ sw))        = (bf16)s0[r];
      *(bf16*)(pw + q_*64 + ((32 + (li << 1)) ^ sw)) = (bf16)s1[r];
    }
    {
      int sw = ((li ^ (li >> 2)) & 3) << 4;
      bf16x8 pa = *(const bf16x8*)(pw + li*64 + ((lg << 4) ^ sw));
      #pragma unroll
      for (int d = 0; d < 4; d++) {
        int dd = (d << 4) + li;
        int fdd = dd ^ ((dd >> 3) & 7);
        bf16x8 vb = *(const bf16x8*)(VS + (lg << 9) + (fdd << 3));
        zacc[d] = MFMA(pa, vb, zacc[d]);
      }
    }
  }

  // normalize + store z (col = head*64 + d)
  bf16* zp = z + (tb + qb) * 1024 + (h << 6);
  #pragma unroll
  for (int d = 0; d < 4; d++)
    #pragma unroll
    for (int r = 0; r < 4; r++) {
      float val = zacc[d][r] / lS[r];
      zp[(size_t)((lg << 2) + r) * 1024 + (d << 4) + li] = (bf16)val;
    }
}

// ---------------- launch ----------------------------------------------------
extern "C" void kernel_launch(void* const* d_in, const int* in_sizes, int n_in,
                              void* d_out, int out_size, void* d_ws, size_t ws_size,
                              hipStream_t stream)
{
  const float* x     = (const float*)d_in[0];
  const float* W_K   = (const float*)d_in[1];
  const float* W_Q   = (const float*)d_in[2];
  const float* W_V   = (const float*)d_in[3];
  const float* W_O   = (const float*)d_in[4];
  const float* W_in  = (const float*)d_in[5];
  const float* b_in  = (const float*)d_in[6];
  const float* W_out = (const float*)d_in[7];
  const float* b_out = (const float*)d_in[8];
  float* out = (float*)d_out;

  char* ws = (char*)d_ws;
  bf16*  xb   = (bf16*)ws;  ws += (size_t)8192*1024*2;
  bf16*  wqkv = (bf16*)ws;  ws += (size_t)3072*1024*2;
  bf16*  wo   = (bf16*)ws;  ws += (size_t)1024*1024*2;
  bf16*  win  = (bf16*)ws;  ws += (size_t)4096*1024*2;
  bf16*  wout = (bf16*)ws;  ws += (size_t)1024*4096*2;
  bf16*  qkv  = (bf16*)ws;  ws += (size_t)8192*3072*2;
  bf16*  zb   = (bf16*)ws;  ws += (size_t)8192*1024*2;
  float* x1f  = (float*)ws; ws += (size_t)8192*1024*4;
  bf16*  x1b  = (bf16*)ws;  ws += (size_t)8192*1024*2;
  bf16*  hb   = (bf16*)ws;  // 8192*4096*2

  auto cast = [&](const float* src, bf16* dst, size_t n) {
    int n8 = (int)(n / 8);
    cast_kernel<<<dim3((n8 + 255) / 256), dim3(256), 0, stream>>>(src, dst, n8);
  };
  cast(x,     xb,               (size_t)8192*1024);
  cast(W_Q,   wqkv,             (size_t)1024*1024);   // Q rows 0..1023 (= head*64+h)
  cast(W_K,   wqkv + 1024*1024, (size_t)1024*1024);   // K rows 1024..2047
  cast(W_V,   wqkv + 2048*1024, (size_t)1024*1024);   // V rows 2048..3071
  cast(W_O,   wo,               (size_t)1024*1024);
  cast(W_in,  win,              (size_t)4096*1024);
  cast(W_out, wout,             (size_t)1024*4096);

  // QKV = x @ Wqkv^T    [8192 x 3072]
  gemm_bt<0><<<dim3(24, 64), 256, 0, stream>>>(xb, wqkv, nullptr, qkv, nullptr, nullptr, 8192, 3072, 1024);
  // causal attention -> z [8192 x 1024]
  attn_kernel<<<dim3(2048), 256, 0, stream>>>(qkv, zb);
  // x1 = x + z @ W_O^T  (f32 + bf16 copies)
  gemm_bt<1><<<dim3(8, 64), 256, 0, stream>>>(zb, wo, x1f, x1b, x, nullptr, 8192, 1024, 1024);
  // h = gelu(x1 @ W_in^T + b_in)   [8192 x 4096] bf16
  gemm_bt<2><<<dim3(32, 64), 256, 0, stream>>>(x1b, win, nullptr, hb, nullptr, b_in, 8192, 4096, 1024);
  // out = x1 + h @ W_out^T + b_out  (fp32)
  gemm_bt<3><<<dim3(8, 64), 256, 0, stream>>>(hb, wout, out, nullptr, x1f, b_out, 8192, 1024, 4096);
}

// Round 2
// 451.663 us; speedup vs baseline: 1.4999x; 1.4999x over previous
//
#include <hip/hip_runtime.h>
#include <hip/hip_bf16.h>
#include <math.h>

typedef __bf16 bf16;
typedef __bf16 bf16x8 __attribute__((ext_vector_type(8)));
typedef __bf16 bf16x4 __attribute__((ext_vector_type(4)));
typedef float  f32x4  __attribute__((ext_vector_type(4)));

#define MFMA(a,b,c) __builtin_amdgcn_mfma_f32_16x16x32_bf16(a,b,c,0,0,0)

__device__ __forceinline__ void gload16(const void* g, void* l) {
  __builtin_amdgcn_global_load_lds((__attribute__((address_space(1))) void*)(g),
                                   (__attribute__((address_space(3))) void*)(l), 16, 0, 0);
}

// ---------------- fp32 -> bf16 cast (vectorized, G13) ----------------
__global__ void cast_kernel(const float* __restrict__ in, bf16* __restrict__ out, int n8) {
  int i = blockIdx.x * 256 + threadIdx.x;
  if (i >= n8) return;
  const float4* p = (const float4*)in;
  float4 a = p[2*i], b = p[2*i+1];
  bf16x8 v;
  v[0]=(bf16)a.x; v[1]=(bf16)a.y; v[2]=(bf16)a.z; v[3]=(bf16)a.w;
  v[4]=(bf16)b.x; v[5]=(bf16)b.y; v[6]=(bf16)b.z; v[7]=(bf16)b.w;
  *(bf16x8*)(out + (size_t)8*i) = v;
}

// ---------------- m97-style 128x128 GEMM, C = A @ B^T, bf16 in / fp32 acc ----
template<int EPI>
__global__ __launch_bounds__(256) void gemm_bt(
    const bf16* __restrict__ A, const bf16* __restrict__ B,
    float* __restrict__ outf, bf16* __restrict__ outb,
    const float* __restrict__ add, const float* __restrict__ bias,
    int M, int N, int K)
{
  __shared__ bf16 As[128*32];
  __shared__ bf16 Bs[128*32];
  const int tid = threadIdx.x;
  const int w = tid >> 6, l = tid & 63, lg = l >> 4, li = l & 15;
  const int m0 = blockIdx.y << 7, n0 = blockIdx.x << 7;
  const int wm = (w >> 1) << 6, wn = (w & 1) << 6;

  const bf16* ga = A + (size_t)(m0 + (tid >> 2)) * K + ((tid & 3) << 3);
  const bf16* gb = B + (size_t)(n0 + (tid >> 2)) * K + ((tid & 3) << 3);
  const size_t half = (size_t)64 * K;

  f32x4 acc[4][4] = {};

  for (int k0 = 0; k0 < K; k0 += 32) {
    __syncthreads();
    gload16(ga + k0,        As + (w << 9));
    gload16(ga + k0 + half, As + 2048 + (w << 9));
    gload16(gb + k0,        Bs + (w << 9));
    gload16(gb + k0 + half, Bs + 2048 + (w << 9));
    __syncthreads();

    bf16x8 af[4], bfv[4];
    #pragma unroll
    for (int i = 0; i < 4; i++)
      af[i] = *(const bf16x8*)(As + (size_t)(wm + (i << 4) + li) * 32 + (lg << 3));
    #pragma unroll
    for (int i = 0; i < 4; i++)
      bfv[i] = *(const bf16x8*)(Bs + (size_t)(wn + (i << 4) + li) * 32 + (lg << 3));
    #pragma unroll
    for (int mi = 0; mi < 4; mi++)
      #pragma unroll
      for (int ni = 0; ni < 4; ni++)
        acc[mi][ni] = MFMA(af[mi], bfv[ni], acc[mi][ni]);
  }

  #pragma unroll
  for (int mi = 0; mi < 4; mi++) {
    const int row = m0 + wm + (mi << 4) + (lg << 2);
    #pragma unroll
    for (int ni = 0; ni < 4; ni++) {
      const int col = n0 + wn + (ni << 4) + li;
      #pragma unroll
      for (int r = 0; r < 4; r++) {
        const size_t idx = (size_t)(row + r) * N + col;
        float v = acc[mi][ni][r];
        if (EPI == 0) {
          outb[idx] = (bf16)v;
        } else if (EPI == 1) {
          float s = v + add[idx];
          outf[idx] = s; outb[idx] = (bf16)s;
        } else if (EPI == 2) {
          float s = v + bias[col];
          s = 0.5f * s * (1.0f + erff(s * 0.70710678118654752f));
          outb[idx] = (bf16)s;
        } else {
          outf[idx] = v + bias[col] + add[idx];
        }
      }
    }
  }
}

// ---------------- causal flash attention (v2) --------------------------------
// Swapped QK^T (lane owns one q-row), KVBLK=64, paired q-tiles for balance.
// Block = 256 thr = 4 waves; block handles q-tiles (31-pr) then (pr), 64 rows
// each; wave owns 16 rows (q = qw + li).
__global__ __launch_bounds__(256) void attn_kernel(const bf16* __restrict__ qkv,
                                                   bf16* __restrict__ z)
{
  __shared__ bf16 Ksh[64*64];   // row p (0..63), chunk-XOR-swizzled: slot c holds chunk c^(p&7)
  __shared__ bf16 VS[64*64];    // [kg=key>>3][f(dd)][j=key&7], f(dd)=dd^((dd>>3)&7)
  __shared__ bf16 Pl[4*16*64];  // per-wave P [16 q rows][64 keys], 32B-XOR swizzled by li&3

  const int tid = threadIdx.x;
  const int w = tid >> 6, l = tid & 63, lg = l >> 4, li = l & 15;
  const int pr = blockIdx.x & 15, bh = blockIdx.x >> 4;
  const int h = bh & 15, b = bh >> 4;
  const size_t tb = (size_t)b * 2048;

  // staging mapping: thread covers rows {srow, srow+32}, 16B chunk sc
  const int srow = tid >> 3, sc = tid & 7;
  const bf16* Kg = qkv + (tb + srow) * 3072 + 1024 + (h << 6) + ((sc ^ (srow & 7)) << 3);
  const bf16* Vg = qkv + (tb + srow) * 3072 + 2048 + (h << 6) + (sc << 3);
  const int vkg0 = (srow >> 3) << 9;  // (srow>>3)*512
  const int vj   = srow & 7;

  char* pw = (char*)Pl + (w << 11) + li * 128;  // wave-private P row base
  const int psw = (li & 3) << 5;                // P swizzle (bits 5-6)

  for (int hf = 0; hf < 2; ++hf) {
    const int qt = hf ? pr : (31 - pr);          // heavy tile first
    const int q0 = qt << 6;
    const int qw = q0 + (w << 4);

    // Q fragments (row = qw+li), scale 1/sqrt(64) folded in (exact pow2)
    const bf16* Qp = qkv + (tb + qw + li) * 3072 + (h << 6);
    bf16x8 qa0 = *(const bf16x8*)(Qp + (lg << 3));
    bf16x8 qa1 = *(const bf16x8*)(Qp + 32 + (lg << 3));
    #pragma unroll
    for (int e = 0; e < 8; e++) {
      qa0[e] = (bf16)((float)qa0[e] * 0.125f);
      qa1[e] = (bf16)((float)qa1[e] * 0.125f);
    }

    f32x4 zacc[4] = {};
    float mR = -1e30f, lS = 0.f;

    const int nkt = qt + 1;
    for (int kt = 0; kt < nkt; ++kt) {
      const int pb = kt << 6;
      const size_t roff = (size_t)pb * 3072;
      __syncthreads();
      // K: 8KB via 2 passes of global_load_lds (source pre-XOR-swizzled)
      gload16(Kg + roff,                     Ksh + (w << 9));
      gload16(Kg + roff + (size_t)32*3072,   Ksh + 2048 + (w << 9));
      // V: reg-stage + scatter into [kg][f(dd)][j]
      #pragma unroll
      for (int pass = 0; pass < 2; ++pass) {
        bf16x8 vv = *(const bf16x8*)(Vg + roff + (size_t)pass*32*3072);
        const int kgb = (pass << 11) + vkg0;
        #pragma unroll
        for (int j2 = 0; j2 < 8; j2++) {
          int dd = (sc << 3) + j2;
          VS[kgb + ((dd ^ sc) << 3) + vj] = vv[j2];
        }
      }
      __syncthreads();

      // S^T = K Q^T : C col = q-row (li), C row = key-in-16 (lg*4+r), sub = key/16
      f32x4 s[4];
      #pragma unroll
      for (int sub = 0; sub < 4; ++sub) {
        const char* kr = (const char*)Ksh + ((sub << 4) + li) * 128;
        const int c0 = (lg ^ (li & 7)) << 4;
        bf16x8 kb0 = *(const bf16x8*)(kr + c0);
        bf16x8 kb1 = *(const bf16x8*)(kr + (c0 ^ 64));
        f32x4 acc = {};
        acc = MFMA(kb0, qa0, acc);
        acc = MFMA(kb1, qa1, acc);
        s[sub] = acc;
      }

      // causal mask (diagonal tile only; wave-uniform branch)
      if (pb + 63 > qw) {
        #pragma unroll
        for (int sub = 0; sub < 4; ++sub)
          #pragma unroll
          for (int r = 0; r < 4; ++r)
            if (pb + (sub << 4) + (lg << 2) + r > qw + li) s[sub][r] = -1e30f;
      }

      // online softmax: lane owns one q-row; reduce over lg groups (2 shfls)
      f32x4 m4;
      #pragma unroll
      for (int r = 0; r < 4; ++r)
        m4[r] = fmaxf(fmaxf(s[0][r], s[1][r]), fmaxf(s[2][r], s[3][r]));
      float mx = fmaxf(fmaxf(m4[0], m4[1]), fmaxf(m4[2], m4[3]));
      mx = fmaxf(mx, __shfl_xor(mx, 16));
      mx = fmaxf(mx, __shfl_xor(mx, 32));

      float mn = mR;
      if (!__all(mx <= mR + 8.0f)) {           // defer-max (T13, THR=8)
        mn = fmaxf(mR, mx);
        float c = __expf(mR - mn);
        mR = mn;
        lS *= c;
        float cr0 = __shfl(c, (lg << 2) + 0);
        float cr1 = __shfl(c, (lg << 2) + 1);
        float cr2 = __shfl(c, (lg << 2) + 2);
        float cr3 = __shfl(c, (lg << 2) + 3);
        #pragma unroll
        for (int d = 0; d < 4; ++d) {
          zacc[d][0] *= cr0; zacc[d][1] *= cr1;
          zacc[d][2] *= cr2; zacc[d][3] *= cr3;
        }
      }

      f32x4 p[4];
      #pragma unroll
      for (int sub = 0; sub < 4; ++sub)
        #pragma unroll
        for (int r = 0; r < 4; ++r)
          p[sub][r] = __expf(s[sub][r] - mn);
      f32x4 t4 = p[0] + p[1] + p[2] + p[3];
      float sm = (t4[0] + t4[1]) + (t4[2] + t4[3]);
      sm += __shfl_xor(sm, 16);
      sm += __shfl_xor(sm, 32);
      lS += sm;

      // pack P (keys lg*4+r consecutive) -> swizzled wave-private LDS
      #pragma unroll
      for (int sub = 0; sub < 4; ++sub) {
        bf16x4 pk;
        pk[0] = (bf16)p[sub][0]; pk[1] = (bf16)p[sub][1];
        pk[2] = (bf16)p[sub][2]; pk[3] = (bf16)p[sub][3];
        *(bf16x4*)(pw + (((sub << 5) + (lg << 3)) ^ psw)) = pk;
      }

      // PV: pa = P[row li][keys kc*32+lg*8..+7], vb = V[keys][d=dblk*16+li]
      #pragma unroll
      for (int kc = 0; kc < 2; ++kc) {
        bf16x8 pa = *(const bf16x8*)(pw + (((kc << 6) + (lg << 4)) ^ psw));
        #pragma unroll
        for (int d = 0; d < 4; ++d) {
          int dd = (d << 4) + li;
          int f = dd ^ ((dd >> 3) & 7);
          bf16x8 vb = *(const bf16x8*)(VS + (((kc << 2) + lg) << 9) + (f << 3));
          zacc[d] = MFMA(pa, vb, zacc[d]);
        }
      }
    }

    // normalize + store z (row q = qw + lg*4 + r, col = h*64 + d*16 + li)
    float rls[4];
    #pragma unroll
    for (int r = 0; r < 4; ++r) rls[r] = 1.0f / __shfl(lS, (lg << 2) + r);
    bf16* zp = z + (tb + qw) * 1024 + (h << 6);
    #pragma unroll
    for (int d = 0; d < 4; ++d)
      #pragma unroll
      for (int r = 0; r < 4; ++r)
        zp[(size_t)((lg << 2) + r) * 1024 + (d << 4) + li] = (bf16)(zacc[d][r] * rls[r]);
  }
}

// ---------------- launch ----------------------------------------------------
extern "C" void kernel_launch(void* const* d_in, const int* in_sizes, int n_in,
                              void* d_out, int out_size, void* d_ws, size_t ws_size,
                              hipStream_t stream)
{
  const float* x     = (const float*)d_in[0];
  const float* W_K   = (const float*)d_in[1];
  const float* W_Q   = (const float*)d_in[2];
  const float* W_V   = (const float*)d_in[3];
  const float* W_O   = (const float*)d_in[4];
  const float* W_in  = (const float*)d_in[5];
  const float* b_in  = (const float*)d_in[6];
  const float* W_out = (const float*)d_in[7];
  const float* b_out = (const float*)d_in[8];
  float* out = (float*)d_out;

  char* ws = (char*)d_ws;
  bf16*  xb   = (bf16*)ws;  ws += (size_t)8192*1024*2;
  bf16*  wqkv = (bf16*)ws;  ws += (size_t)3072*1024*2;
  bf16*  wo   = (bf16*)ws;  ws += (size_t)1024*1024*2;
  bf16*  win  = (bf16*)ws;  ws += (size_t)4096*1024*2;
  bf16*  wout = (bf16*)ws;  ws += (size_t)1024*4096*2;
  bf16*  qkv  = (bf16*)ws;  ws += (size_t)8192*3072*2;
  bf16*  zb   = (bf16*)ws;  ws += (size_t)8192*1024*2;
  float* x1f  = (float*)ws; ws += (size_t)8192*1024*4;
  bf16*  x1b  = (bf16*)ws;  ws += (size_t)8192*1024*2;
  bf16*  hb   = (bf16*)ws;  // 8192*4096*2

  auto cast = [&](const float* src, bf16* dst, size_t n) {
    int n8 = (int)(n / 8);
    cast_kernel<<<dim3((n8 + 255) / 256), dim3(256), 0, stream>>>(src, dst, n8);
  };
  cast(x,     xb,               (size_t)8192*1024);
  cast(W_Q,   wqkv,             (size_t)1024*1024);
  cast(W_K,   wqkv + 1024*1024, (size_t)1024*1024);
  cast(W_V,   wqkv + 2048*1024, (size_t)1024*1024);
  cast(W_O,   wo,               (size_t)1024*1024);
  cast(W_in,  win,              (size_t)4096*1024);
  cast(W_out, wout,             (size_t)1024*4096);

  // QKV = x @ Wqkv^T    [8192 x 3072]
  gemm_bt<0><<<dim3(24, 64), 256, 0, stream>>>(xb, wqkv, nullptr, qkv, nullptr, nullptr, 8192, 3072, 1024);
  // causal attention -> z [8192 x 1024]  (1024 balanced blocks: paired q-tiles)
  attn_kernel<<<dim3(1024), 256, 0, stream>>>(qkv, zb);
  // x1 = x + z @ W_O^T  (f32 + bf16 copies)
  gemm_bt<1><<<dim3(8, 64), 256, 0, stream>>>(zb, wo, x1f, x1b, x, nullptr, 8192, 1024, 1024);
  // h = gelu(x1 @ W_in^T + b_in)   [8192 x 4096] bf16
  gemm_bt<2><<<dim3(32, 64), 256, 0, stream>>>(x1b, win, nullptr, hb, nullptr, b_in, 8192, 4096, 1024);
  // out = x1 + h @ W_out^T + b_out  (fp32)
  gemm_bt<3><<<dim3(8, 64), 256, 0, stream>>>(hb, wout, out, nullptr, x1f, b_out, 8192, 1024, 4096);
}

// Round 3
// 432.739 us; speedup vs baseline: 1.5655x; 1.0437x over previous
//
#include <hip/hip_runtime.h>
#include <hip/hip_bf16.h>
#include <math.h>

typedef __bf16 bf16;
typedef __bf16 bf16x8 __attribute__((ext_vector_type(8)));
typedef __bf16 bf16x4 __attribute__((ext_vector_type(4)));
typedef float  f32x4  __attribute__((ext_vector_type(4)));

#define MFMA(a,b,c) __builtin_amdgcn_mfma_f32_16x16x32_bf16(a,b,c,0,0,0)

__device__ __forceinline__ void gload16(const void* g, void* l) {
  __builtin_amdgcn_global_load_lds((__attribute__((address_space(1))) void*)(g),
                                   (__attribute__((address_space(3))) void*)(l), 16, 0, 0);
}

// ---------------- fp32 -> bf16 cast ----------------
__global__ void cast_kernel(const float* __restrict__ in, bf16* __restrict__ out, int n8) {
  int i = blockIdx.x * 256 + threadIdx.x;
  if (i >= n8) return;
  const float4* p = (const float4*)in;
  float4 a = p[2*i], b = p[2*i+1];
  bf16x8 v;
  v[0]=(bf16)a.x; v[1]=(bf16)a.y; v[2]=(bf16)a.z; v[3]=(bf16)a.w;
  v[4]=(bf16)b.x; v[5]=(bf16)b.y; v[6]=(bf16)b.z; v[7]=(bf16)b.w;
  *(bf16x8*)(out + (size_t)8*i) = v;
}

// ============ 256x256 8-phase GEMM (m201 template), C = A @ B^T =============
// A:[M][K] bf16, B:[N][K] bf16. 512 thr = 8 waves (2M x 4N), BK=64, LDS 128KB.
// EPI: 0=bf16 out; 1=+add -> f32+bf16; 2=+bias,GELU -> bf16; 3=+bias+add -> f32
#define BAR_WAIT() { __builtin_amdgcn_s_barrier(); \
                     asm volatile("s_waitcnt lgkmcnt(0)" ::: "memory"); \
                     __builtin_amdgcn_sched_barrier(0); }
#define BAR_END()  { __builtin_amdgcn_s_barrier(); \
                     __builtin_amdgcn_sched_barrier(0); }

#define LDA_PH(MI2) { _Pragma("unroll") for (int i = 0; i < 4; i++) { \
    af[i][0] = *(const bf16x8*)(lds + ab + ((((MI2)<<2)+i) << 11) + rdswz); \
    af[i][1] = *(const bf16x8*)(lds + ab + ((((MI2)<<2)+i) << 11) + 1024 + rdswz); } }

#define LDB_PH(NI2) { _Pragma("unroll") for (int n = 0; n < 2; n++) { \
    bfr[((NI2)<<1)+n][0] = *(const bf16x8*)(lds + bb + (((((NI2)<<1)+n)) << 11) + rdswz); \
    bfr[((NI2)<<1)+n][1] = *(const bf16x8*)(lds + bb + (((((NI2)<<1)+n)) << 11) + 1024 + rdswz); } }

#define MM_PH(MI2, NI2) { __builtin_amdgcn_s_setprio(1); \
    _Pragma("unroll") for (int i = 0; i < 4; i++) \
      _Pragma("unroll") for (int n = 0; n < 2; n++) { \
        acc[((MI2)<<2)+i][((NI2)<<1)+n] = MFMA(af[i][0], bfr[((NI2)<<1)+n][0], acc[((MI2)<<2)+i][((NI2)<<1)+n]); \
        acc[((MI2)<<2)+i][((NI2)<<1)+n] = MFMA(af[i][1], bfr[((NI2)<<1)+n][1], acc[((MI2)<<2)+i][((NI2)<<1)+n]); } \
    __builtin_amdgcn_s_setprio(0); }

template<int EPI>
__global__ __launch_bounds__(512, 2) void gemm256(
    const bf16* __restrict__ A, const bf16* __restrict__ B,
    float* __restrict__ outf, bf16* __restrict__ outb,
    const float* __restrict__ add, const float* __restrict__ bias,
    int M, int N, int K, int gx)
{
  __shared__ __attribute__((aligned(128))) char lds[131072];
  const int tid = threadIdx.x;
  const int w = tid >> 6, l = tid & 63, lg = l >> 4, li = l & 15;
  const int wm = w >> 2, wn = w & 3;

  // bijective XCD swizzle (m204)
  const int nwg = gridDim.x, orig = blockIdx.x;
  const int q = nwg >> 3, r = nwg & 7;
  const int xcd = orig & 7, pos = orig >> 3;
  const int wg = (xcd < r ? xcd*(q+1) : r*(q+1) + (xcd-r)*q) + pos;
  const int m0 = (wg / gx) << 8, n0 = (wg % gx) << 8;

  const int NT = K >> 6;

  // staging lane mapping: dest byte (linear) = i*8192 + tid*16 within half-region;
  // source coords = swizzle-inverse (involution): row same, col chunk ^16 elems when bit9 set
  const int srow = ((tid >> 7) << 4) + ((tid >> 2) & 15);
  const int scol = (((tid >> 6) & 1) << 5) + (((tid & 3) << 3) ^ (((tid >> 5) & 1) << 4));
  const bf16* sA = A + (size_t)(m0 + srow) * K + scol;
  const bf16* sB = B + (size_t)(n0 + srow) * K + scol;
  char* const myl = lds + (w << 10);

  auto STG = [&](const bf16* s0, int buf, int isB, int h, int tt) {
    const bf16* g = s0 + ((size_t)(h << 7)) * K + ((size_t)tt << 6);
    char* lb = myl + (buf << 16) + (isB << 15) + (h << 14);
    gload16(g, lb);
    gload16(g + ((size_t)K << 6), lb + 8192);
  };

  // ds-read swizzled lane offset: li*64 + (lg*16 ^ ((li&8)<<2))
  const int rdswz = (li << 6) + ((lg << 4) ^ ((li & 8) << 2));

  f32x4 acc[8][4] = {};
  bf16x8 af[4][2], bfr[4][2];

  // prologue: K-tile0 (B_lo,B_hi,A_lo,A_hi) -> buf0; K-tile1 first 3 -> buf1
  STG(sB, 0, 1, 0, 0); STG(sB, 0, 1, 1, 0); STG(sA, 0, 0, 0, 0); STG(sA, 0, 0, 1, 0);
  asm volatile("s_waitcnt vmcnt(4)" ::: "memory");
  if (NT > 1) {
    STG(sB, 1, 1, 0, 1); STG(sB, 1, 1, 1, 1); STG(sA, 1, 0, 0, 1);
    asm volatile("s_waitcnt vmcnt(6)" ::: "memory");
  } else {
    asm volatile("s_waitcnt vmcnt(0)" ::: "memory");
  }
  __builtin_amdgcn_s_barrier();
  __builtin_amdgcn_sched_barrier(0);

  for (int t = 0; t < NT; ++t) {
    const int cur = t & 1;
    const int ab = (cur << 16) + (wm << 14);
    const int bb = (cur << 16) + 32768 + (wn << 13);

    // phase 1: A-frags mi0-3 + B-frags ni0-1; stage A_hi(t+1) -> buf cur^1
    LDA_PH(0); LDB_PH(0);
    if (t + 1 < NT) STG(sA, (t + 1) & 1, 0, 1, t + 1);
    BAR_WAIT(); MM_PH(0, 0); BAR_END();

    // phase 2: B-frags ni2-3; stage B_lo(t+2) -> buf cur
    LDB_PH(1);
    if (t + 2 < NT) STG(sB, cur, 1, 0, t + 2);
    BAR_WAIT(); MM_PH(0, 1); BAR_END();

    // phase 3: A-frags mi4-7; stage B_hi(t+2)
    LDA_PH(1);
    if (t + 2 < NT) STG(sB, cur, 1, 1, t + 2);
    BAR_WAIT(); MM_PH(1, 0); BAR_END();

    // phase 4: stage A_lo(t+2); counted vmcnt before closing barrier
    if (t + 2 < NT) STG(sA, cur, 0, 0, t + 2);
    BAR_WAIT(); MM_PH(1, 1);
    if (t + 2 < NT) { asm volatile("s_waitcnt vmcnt(6)" ::: "memory"); }
    else            { asm volatile("s_waitcnt vmcnt(0)" ::: "memory"); }
    BAR_END();
  }

  // epilogue: row = m0+wm*128+mi*16+lg*4+r, col = n0+wn*64+ni*16+li
  #pragma unroll
  for (int mi = 0; mi < 8; mi++) {
    const int row = m0 + (wm << 7) + (mi << 4) + (lg << 2);
    #pragma unroll
    for (int ni = 0; ni < 4; ni++) {
      const int col = n0 + (wn << 6) + (ni << 4) + li;
      #pragma unroll
      for (int r2 = 0; r2 < 4; r2++) {
        const size_t idx = (size_t)(row + r2) * N + col;
        float v = acc[mi][ni][r2];
        if (EPI == 0) {
          outb[idx] = (bf16)v;
        } else if (EPI == 1) {
          float s = v + add[idx];
          outf[idx] = s; outb[idx] = (bf16)s;
        } else if (EPI == 2) {
          float s = v + bias[col];
          float u = s * (0.7978845608f + 0.0356774081f * s * s);
          float g = s / (1.0f + __expf(-2.0f * u));   // tanh-form GELU
          outb[idx] = (bf16)g;
        } else {
          outf[idx] = v + bias[col] + add[idx];
        }
      }
    }
  }
}

// ---------------- m97-style 128x128 GEMM (kept for MLP2, K=4096) ------------
template<int EPI>
__global__ __launch_bounds__(256) void gemm_bt(
    const bf16* __restrict__ A, const bf16* __restrict__ B,
    float* __restrict__ outf, bf16* __restrict__ outb,
    const float* __restrict__ add, const float* __restrict__ bias,
    int M, int N, int K)
{
  __shared__ bf16 As[128*32];
  __shared__ bf16 Bs[128*32];
  const int tid = threadIdx.x;
  const int w = tid >> 6, l = tid & 63, lg = l >> 4, li = l & 15;
  const int m0 = blockIdx.y << 7, n0 = blockIdx.x << 7;
  const int wm = (w >> 1) << 6, wn = (w & 1) << 6;

  const bf16* ga = A + (size_t)(m0 + (tid >> 2)) * K + ((tid & 3) << 3);
  const bf16* gb = B + (size_t)(n0 + (tid >> 2)) * K + ((tid & 3) << 3);
  const size_t half = (size_t)64 * K;

  f32x4 acc[4][4] = {};

  for (int k0 = 0; k0 < K; k0 += 32) {
    __syncthreads();
    gload16(ga + k0,        As + (w << 9));
    gload16(ga + k0 + half, As + 2048 + (w << 9));
    gload16(gb + k0,        Bs + (w << 9));
    gload16(gb + k0 + half, Bs + 2048 + (w << 9));
    __syncthreads();

    bf16x8 af[4], bfv[4];
    #pragma unroll
    for (int i = 0; i < 4; i++)
      af[i] = *(const bf16x8*)(As + (size_t)(wm + (i << 4) + li) * 32 + (lg << 3));
    #pragma unroll
    for (int i = 0; i < 4; i++)
      bfv[i] = *(const bf16x8*)(Bs + (size_t)(wn + (i << 4) + li) * 32 + (lg << 3));
    #pragma unroll
    for (int mi = 0; mi < 4; mi++)
      #pragma unroll
      for (int ni = 0; ni < 4; ni++)
        acc[mi][ni] = MFMA(af[mi], bfv[ni], acc[mi][ni]);
  }

  #pragma unroll
  for (int mi = 0; mi < 4; mi++) {
    const int row = m0 + wm + (mi << 4) + (lg << 2);
    #pragma unroll
    for (int ni = 0; ni < 4; ni++) {
      const int col = n0 + wn + (ni << 4) + li;
      #pragma unroll
      for (int r = 0; r < 4; r++) {
        const size_t idx = (size_t)(row + r) * N + col;
        float v = acc[mi][ni][r];
        if (EPI == 0) {
          outb[idx] = (bf16)v;
        } else if (EPI == 1) {
          float s = v + add[idx];
          outf[idx] = s; outb[idx] = (bf16)s;
        } else if (EPI == 2) {
          float s = v + bias[col];
          s = 0.5f * s * (1.0f + erff(s * 0.70710678118654752f));
          outb[idx] = (bf16)s;
        } else {
          outf[idx] = v + bias[col] + add[idx];
        }
      }
    }
  }
}

// ---------------- causal flash attention (v2, unchanged) --------------------
__global__ __launch_bounds__(256) void attn_kernel(const bf16* __restrict__ qkv,
                                                   bf16* __restrict__ z)
{
  __shared__ bf16 Ksh[64*64];
  __shared__ bf16 VS[64*64];
  __shared__ bf16 Pl[4*16*64];

  const int tid = threadIdx.x;
  const int w = tid >> 6, l = tid & 63, lg = l >> 4, li = l & 15;
  const int pr = blockIdx.x & 15, bh = blockIdx.x >> 4;
  const int h = bh & 15, b = bh >> 4;
  const size_t tb = (size_t)b * 2048;

  const int srow = tid >> 3, sc = tid & 7;
  const bf16* Kg = qkv + (tb + srow) * 3072 + 1024 + (h << 6) + ((sc ^ (srow & 7)) << 3);
  const bf16* Vg = qkv + (tb + srow) * 3072 + 2048 + (h << 6) + (sc << 3);
  const int vkg0 = (srow >> 3) << 9;
  const int vj   = srow & 7;

  char* pw = (char*)Pl + (w << 11) + li * 128;
  const int psw = (li & 3) << 5;

  for (int hf = 0; hf < 2; ++hf) {
    const int qt = hf ? pr : (31 - pr);
    const int q0 = qt << 6;
    const int qw = q0 + (w << 4);

    const bf16* Qp = qkv + (tb + qw + li) * 3072 + (h << 6);
    bf16x8 qa0 = *(const bf16x8*)(Qp + (lg << 3));
    bf16x8 qa1 = *(const bf16x8*)(Qp + 32 + (lg << 3));
    #pragma unroll
    for (int e = 0; e < 8; e++) {
      qa0[e] = (bf16)((float)qa0[e] * 0.125f);
      qa1[e] = (bf16)((float)qa1[e] * 0.125f);
    }

    f32x4 zacc[4] = {};
    float mR = -1e30f, lS = 0.f;

    const int nkt = qt + 1;
    for (int kt = 0; kt < nkt; ++kt) {
      const int pb = kt << 6;
      const size_t roff = (size_t)pb * 3072;
      __syncthreads();
      gload16(Kg + roff,                   Ksh + (w << 9));
      gload16(Kg + roff + (size_t)32*3072, Ksh + 2048 + (w << 9));
      #pragma unroll
      for (int pass = 0; pass < 2; ++pass) {
        bf16x8 vv = *(const bf16x8*)(Vg + roff + (size_t)pass*32*3072);
        const int kgb = (pass << 11) + vkg0;
        #pragma unroll
        for (int j2 = 0; j2 < 8; j2++) {
          int dd = (sc << 3) + j2;
          VS[kgb + ((dd ^ sc) << 3) + vj] = vv[j2];
        }
      }
      __syncthreads();

      f32x4 s[4];
      #pragma unroll
      for (int sub = 0; sub < 4; ++sub) {
        const char* kr = (const char*)Ksh + ((sub << 4) + li) * 128;
        const int c0 = (lg ^ (li & 7)) << 4;
        bf16x8 kb0 = *(const bf16x8*)(kr + c0);
        bf16x8 kb1 = *(const bf16x8*)(kr + (c0 ^ 64));
        f32x4 a2 = {};
        a2 = MFMA(kb0, qa0, a2);
        a2 = MFMA(kb1, qa1, a2);
        s[sub] = a2;
      }

      if (pb + 63 > qw) {
        #pragma unroll
        for (int sub = 0; sub < 4; ++sub)
          #pragma unroll
          for (int r = 0; r < 4; ++r)
            if (pb + (sub << 4) + (lg << 2) + r > qw + li) s[sub][r] = -1e30f;
      }

      f32x4 m4;
      #pragma unroll
      for (int r = 0; r < 4; ++r)
        m4[r] = fmaxf(fmaxf(s[0][r], s[1][r]), fmaxf(s[2][r], s[3][r]));
      float mx = fmaxf(fmaxf(m4[0], m4[1]), fmaxf(m4[2], m4[3]));
      mx = fmaxf(mx, __shfl_xor(mx, 16));
      mx = fmaxf(mx, __shfl_xor(mx, 32));

      float mn = mR;
      if (!__all(mx <= mR + 8.0f)) {
        mn = fmaxf(mR, mx);
        float c = __expf(mR - mn);
        mR = mn;
        lS *= c;
        float cr0 = __shfl(c, (lg << 2) + 0);
        float cr1 = __shfl(c, (lg << 2) + 1);
        float cr2 = __shfl(c, (lg << 2) + 2);
        float cr3 = __shfl(c, (lg << 2) + 3);
        #pragma unroll
        for (int d = 0; d < 4; ++d) {
          zacc[d][0] *= cr0; zacc[d][1] *= cr1;
          zacc[d][2] *= cr2; zacc[d][3] *= cr3;
        }
      }

      f32x4 p[4];
      #pragma unroll
      for (int sub = 0; sub < 4; ++sub)
        #pragma unroll
        for (int r = 0; r < 4; ++r)
          p[sub][r] = __expf(s[sub][r] - mn);
      f32x4 t4 = p[0] + p[1] + p[2] + p[3];
      float sm = (t4[0] + t4[1]) + (t4[2] + t4[3]);
      sm += __shfl_xor(sm, 16);
      sm += __shfl_xor(sm, 32);
      lS += sm;

      #pragma unroll
      for (int sub = 0; sub < 4; ++sub) {
        bf16x4 pk;
        pk[0] = (bf16)p[sub][0]; pk[1] = (bf16)p[sub][1];
        pk[2] = (bf16)p[sub][2]; pk[3] = (bf16)p[sub][3];
        *(bf16x4*)(pw + (((sub << 5) + (lg << 3)) ^ psw)) = pk;
      }

      #pragma unroll
      for (int kc = 0; kc < 2; ++kc) {
        bf16x8 pa = *(const bf16x8*)(pw + (((kc << 6) + (lg << 4)) ^ psw));
        #pragma unroll
        for (int d = 0; d < 4; ++d) {
          int dd = (d << 4) + li;
          int f = dd ^ ((dd >> 3) & 7);
          bf16x8 vb = *(const bf16x8*)(VS + (((kc << 2) + lg) << 9) + (f << 3));
          zacc[d] = MFMA(pa, vb, zacc[d]);
        }
      }
    }

    float rls[4];
    #pragma unroll
    for (int r = 0; r < 4; ++r) rls[r] = 1.0f / __shfl(lS, (lg << 2) + r);
    bf16* zp = z + (tb + qw) * 1024 + (h << 6);
    #pragma unroll
    for (int d = 0; d < 4; ++d)
      #pragma unroll
      for (int r = 0; r < 4; ++r)
        zp[(size_t)((lg << 2) + r) * 1024 + (d << 4) + li] = (bf16)(zacc[d][r] * rls[r]);
  }
}

// ---------------- launch ----------------------------------------------------
extern "C" void kernel_launch(void* const* d_in, const int* in_sizes, int n_in,
                              void* d_out, int out_size, void* d_ws, size_t ws_size,
                              hipStream_t stream)
{
  const float* x     = (const float*)d_in[0];
  const float* W_K   = (const float*)d_in[1];
  const float* W_Q   = (const float*)d_in[2];
  const float* W_V   = (const float*)d_in[3];
  const float* W_O   = (const float*)d_in[4];
  const float* W_in  = (const float*)d_in[5];
  const float* b_in  = (const float*)d_in[6];
  const float* W_out = (const float*)d_in[7];
  const float* b_out = (const float*)d_in[8];
  float* out = (float*)d_out;

  char* ws = (char*)d_ws;
  bf16*  xb   = (bf16*)ws;  ws += (size_t)8192*1024*2;
  bf16*  wqkv = (bf16*)ws;  ws += (size_t)3072*1024*2;
  bf16*  wo   = (bf16*)ws;  ws += (size_t)1024*1024*2;
  bf16*  win  = (bf16*)ws;  ws += (size_t)4096*1024*2;
  bf16*  wout = (bf16*)ws;  ws += (size_t)1024*4096*2;
  bf16*  qkv  = (bf16*)ws;  ws += (size_t)8192*3072*2;
  bf16*  zb   = (bf16*)ws;  ws += (size_t)8192*1024*2;
  float* x1f  = (float*)ws; ws += (size_t)8192*1024*4;
  bf16*  x1b  = (bf16*)ws;  ws += (size_t)8192*1024*2;
  bf16*  hb   = (bf16*)ws;  // 8192*4096*2

  auto cast = [&](const float* src, bf16* dst, size_t n) {
    int n8 = (int)(n / 8);
    cast_kernel<<<dim3((n8 + 255) / 256), dim3(256), 0, stream>>>(src, dst, n8);
  };
  cast(x,     xb,               (size_t)8192*1024);
  cast(W_Q,   wqkv,             (size_t)1024*1024);
  cast(W_K,   wqkv + 1024*1024, (size_t)1024*1024);
  cast(W_V,   wqkv + 2048*1024, (size_t)1024*1024);
  cast(W_O,   wo,               (size_t)1024*1024);
  cast(W_in,  win,              (size_t)4096*1024);
  cast(W_out, wout,             (size_t)1024*4096);

  // QKV = x @ Wqkv^T    [8192 x 3072]  (8-phase 256^2, 384 blocks)
  gemm256<0><<<dim3(384), 512, 0, stream>>>(xb, wqkv, nullptr, qkv, nullptr, nullptr, 8192, 3072, 1024, 12);
  // causal attention -> z [8192 x 1024]
  attn_kernel<<<dim3(1024), 256, 0, stream>>>(qkv, zb);
  // x1 = x + z @ W_O^T   (8-phase 256^2, 128 blocks)
  gemm256<1><<<dim3(128), 512, 0, stream>>>(zb, wo, x1f, x1b, x, nullptr, 8192, 1024, 1024, 4);
  // h = gelu(x1 @ W_in^T + b_in)  (8-phase 256^2, 512 blocks)
  gemm256<2><<<dim3(512), 512, 0, stream>>>(x1b, win, nullptr, hb, nullptr, b_in, 8192, 4096, 1024, 16);
  // out = x1 + h @ W_out^T + b_out  (m97 128^2, K=4096)
  gemm_bt<3><<<dim3(8, 64), 256, 0, stream>>>(hb, wout, out, nullptr, x1f, b_out, 8192, 1024, 4096);
}

// Round 4
// 381.493 us; speedup vs baseline: 1.7758x; 1.1343x over previous
//
#include <hip/hip_runtime.h>
#include <hip/hip_bf16.h>
#include <math.h>

typedef __bf16 bf16;
typedef __bf16 bf16x8 __attribute__((ext_vector_type(8)));
typedef __bf16 bf16x4 __attribute__((ext_vector_type(4)));
typedef float  f32x4  __attribute__((ext_vector_type(4)));

#define MFMA(a,b,c) __builtin_amdgcn_mfma_f32_16x16x32_bf16(a,b,c,0,0,0)

__device__ __forceinline__ void gload16(const void* g, void* l) {
  __builtin_amdgcn_global_load_lds((__attribute__((address_space(1))) void*)(g),
                                   (__attribute__((address_space(3))) void*)(l), 16, 0, 0);
}

// ---------------- fp32 -> bf16 cast ----------------
__global__ void cast_kernel(const float* __restrict__ in, bf16* __restrict__ out, int n8) {
  int i = blockIdx.x * 256 + threadIdx.x;
  if (i >= n8) return;
  const float4* p = (const float4*)in;
  float4 a = p[2*i], b = p[2*i+1];
  bf16x8 v;
  v[0]=(bf16)a.x; v[1]=(bf16)a.y; v[2]=(bf16)a.z; v[3]=(bf16)a.w;
  v[4]=(bf16)b.x; v[5]=(bf16)b.y; v[6]=(bf16)b.z; v[7]=(bf16)b.w;
  *(bf16x8*)(out + (size_t)8*i) = v;
}

// shared epilogue math
__device__ __forceinline__ float gelu_t(float s) {
  float u = s * (0.7978845608f + 0.0356774081f * s * s);
  return s / (1.0f + __expf(-2.0f * u));
}

#define BAR_WAIT() { __builtin_amdgcn_s_barrier(); \
                     asm volatile("s_waitcnt lgkmcnt(0)" ::: "memory"); \
                     __builtin_amdgcn_sched_barrier(0); }
#define BAR_END()  { __builtin_amdgcn_s_barrier(); \
                     __builtin_amdgcn_sched_barrier(0); }

// ============ 256x256 8-phase GEMM (m201 template), C = A @ B^T =============
// A:[M][K] bf16, B:[N][K] bf16. 512 thr = 8 waves (2M x 4N), BK=64, LDS 128KB.
#define LDA_PH(MI2) { _Pragma("unroll") for (int i = 0; i < 4; i++) { \
    af[i][0] = *(const bf16x8*)(lds + ab + ((((MI2)<<2)+i) << 11) + rdswz); \
    af[i][1] = *(const bf16x8*)(lds + ab + ((((MI2)<<2)+i) << 11) + 1024 + rdswz); } }

#define LDB_PH(NI2) { _Pragma("unroll") for (int n = 0; n < 2; n++) { \
    bfr[((NI2)<<1)+n][0] = *(const bf16x8*)(lds + bb + (((((NI2)<<1)+n)) << 11) + rdswz); \
    bfr[((NI2)<<1)+n][1] = *(const bf16x8*)(lds + bb + (((((NI2)<<1)+n)) << 11) + 1024 + rdswz); } }

#define MM_PH(MI2, NI2) { __builtin_amdgcn_s_setprio(1); \
    _Pragma("unroll") for (int i = 0; i < 4; i++) \
      _Pragma("unroll") for (int n = 0; n < 2; n++) { \
        acc[((MI2)<<2)+i][((NI2)<<1)+n] = MFMA(af[i][0], bfr[((NI2)<<1)+n][0], acc[((MI2)<<2)+i][((NI2)<<1)+n]); \
        acc[((MI2)<<2)+i][((NI2)<<1)+n] = MFMA(af[i][1], bfr[((NI2)<<1)+n][1], acc[((MI2)<<2)+i][((NI2)<<1)+n]); } \
    __builtin_amdgcn_s_setprio(0); }

template<int EPI>
__global__ __launch_bounds__(512, 2) void gemm256(
    const bf16* __restrict__ A, const bf16* __restrict__ B,
    float* __restrict__ outf, bf16* __restrict__ outb,
    const float* __restrict__ add, const float* __restrict__ bias,
    int M, int N, int K, int gx)
{
  __shared__ __attribute__((aligned(128))) char lds[131072];
  const int tid = threadIdx.x;
  const int w = tid >> 6, l = tid & 63, lg = l >> 4, li = l & 15;
  const int wm = w >> 2, wn = w & 3;

  const int nwg = gridDim.x, orig = blockIdx.x;
  const int q = nwg >> 3, r = nwg & 7;
  const int xcd = orig & 7, pos = orig >> 3;
  const int wg = (xcd < r ? xcd*(q+1) : r*(q+1) + (xcd-r)*q) + pos;
  const int m0 = (wg / gx) << 8, n0 = (wg % gx) << 8;

  const int NT = K >> 6;

  const int srow = ((tid >> 7) << 4) + ((tid >> 2) & 15);
  const int scol = (((tid >> 6) & 1) << 5) + (((tid & 3) << 3) ^ (((tid >> 5) & 1) << 4));
  const bf16* sA = A + (size_t)(m0 + srow) * K + scol;
  const bf16* sB = B + (size_t)(n0 + srow) * K + scol;
  char* const myl = lds + (w << 10);

  auto STG = [&](const bf16* s0, int buf, int isB, int h, int tt) {
    const bf16* g = s0 + ((size_t)(h << 7)) * K + ((size_t)tt << 6);
    char* lb = myl + (buf << 16) + (isB << 15) + (h << 14);
    gload16(g, lb);
    gload16(g + ((size_t)K << 6), lb + 8192);
  };

  const int rdswz = (li << 6) + ((lg << 4) ^ ((li & 8) << 2));

  f32x4 acc[8][4] = {};
  bf16x8 af[4][2], bfr[4][2];

  STG(sB, 0, 1, 0, 0); STG(sB, 0, 1, 1, 0); STG(sA, 0, 0, 0, 0); STG(sA, 0, 0, 1, 0);
  asm volatile("s_waitcnt vmcnt(4)" ::: "memory");
  if (NT > 1) {
    STG(sB, 1, 1, 0, 1); STG(sB, 1, 1, 1, 1); STG(sA, 1, 0, 0, 1);
    asm volatile("s_waitcnt vmcnt(6)" ::: "memory");
  } else {
    asm volatile("s_waitcnt vmcnt(0)" ::: "memory");
  }
  __builtin_amdgcn_s_barrier();
  __builtin_amdgcn_sched_barrier(0);

  for (int t = 0; t < NT; ++t) {
    const int cur = t & 1;
    const int ab = (cur << 16) + (wm << 14);
    const int bb = (cur << 16) + 32768 + (wn << 13);

    LDA_PH(0); LDB_PH(0);
    if (t + 1 < NT) STG(sA, (t + 1) & 1, 0, 1, t + 1);
    BAR_WAIT(); MM_PH(0, 0); BAR_END();

    LDB_PH(1);
    if (t + 2 < NT) STG(sB, cur, 1, 0, t + 2);
    BAR_WAIT(); MM_PH(0, 1); BAR_END();

    LDA_PH(1);
    if (t + 2 < NT) STG(sB, cur, 1, 1, t + 2);
    BAR_WAIT(); MM_PH(1, 0); BAR_END();

    if (t + 2 < NT) STG(sA, cur, 0, 0, t + 2);
    BAR_WAIT(); MM_PH(1, 1);
    if (t + 2 < NT) { asm volatile("s_waitcnt vmcnt(6)" ::: "memory"); }
    else            { asm volatile("s_waitcnt vmcnt(0)" ::: "memory"); }
    BAR_END();
  }

  #pragma unroll
  for (int mi = 0; mi < 8; mi++) {
    const int row = m0 + (wm << 7) + (mi << 4) + (lg << 2);
    #pragma unroll
    for (int ni = 0; ni < 4; ni++) {
      const int col = n0 + (wn << 6) + (ni << 4) + li;
      #pragma unroll
      for (int r2 = 0; r2 < 4; r2++) {
        const size_t idx = (size_t)(row + r2) * N + col;
        float v = acc[mi][ni][r2];
        if (EPI == 0) {
          outb[idx] = (bf16)v;
        } else if (EPI == 1) {
          float s = v + add[idx];
          outf[idx] = s; outb[idx] = (bf16)s;
        } else if (EPI == 2) {
          outb[idx] = (bf16)gelu_t(v + bias[col]);
        } else {
          outf[idx] = v + bias[col] + add[idx];
        }
      }
    }
  }
}

// ============ 256x128 8-phase GEMM (same schedule), C = A @ B^T =============
// 8 waves = 4M x 2N, per-wave 64x64. LDS 96KB: per buf {A: 2x16KB, B: 2x8KB}.
// Grid fills 256 CUs for N=1024 outputs (32 x 8 tiles).
#define N_LDA2(BMI) { _Pragma("unroll") for (int i = 0; i < 2; i++) { \
    af[i][0] = *(const bf16x8*)(lds + abase + (((BMI)+i) << 11) + rdswz); \
    af[i][1] = *(const bf16x8*)(lds + abase + (((BMI)+i) << 11) + 1024 + rdswz); } }

#define N_LDB2(BNI) { _Pragma("unroll") for (int n = 0; n < 2; n++) { \
    bfr[(BNI)+n][0] = *(const bf16x8*)(lds + bbase + (((BNI)+n) << 11) + rdswz); \
    bfr[(BNI)+n][1] = *(const bf16x8*)(lds + bbase + (((BNI)+n) << 11) + 1024 + rdswz); } }

#define N_MMQ(MB, NB) { __builtin_amdgcn_s_setprio(1); \
    _Pragma("unroll") for (int i = 0; i < 2; i++) \
      _Pragma("unroll") for (int n = 0; n < 2; n++) { \
        acc[((MB)<<1)+i][((NB)<<1)+n] = MFMA(af[i][0], bfr[((NB)<<1)+n][0], acc[((MB)<<1)+i][((NB)<<1)+n]); \
        acc[((MB)<<1)+i][((NB)<<1)+n] = MFMA(af[i][1], bfr[((NB)<<1)+n][1], acc[((MB)<<1)+i][((NB)<<1)+n]); } \
    __builtin_amdgcn_s_setprio(0); }

template<int EPI>
__global__ __launch_bounds__(512, 2) void gemm128n(
    const bf16* __restrict__ A, const bf16* __restrict__ B,
    float* __restrict__ outf, bf16* __restrict__ outb,
    const float* __restrict__ add, const float* __restrict__ bias,
    int M, int N, int K, int gx)
{
  __shared__ __attribute__((aligned(128))) char lds[98304];
  const int tid = threadIdx.x;
  const int w = tid >> 6, l = tid & 63, lg = l >> 4, li = l & 15;
  const int wm = w >> 1, wn = w & 1;

  const int nwg = gridDim.x, orig = blockIdx.x;
  const int q = nwg >> 3, r = nwg & 7;
  const int xcd = orig & 7, pos = orig >> 3;
  const int wg = (xcd < r ? xcd*(q+1) : r*(q+1) + (xcd-r)*q) + pos;
  const int m0 = (wg / gx) << 8, n0 = (wg % gx) << 7;

  const int NT = K >> 6;

  const int srow = ((tid >> 7) << 4) + ((tid >> 2) & 15);
  const int scol = (((tid >> 6) & 1) << 5) + (((tid & 3) << 3) ^ (((tid >> 5) & 1) << 4));
  const bf16* sA = A + (size_t)(m0 + srow) * K + scol;
  const bf16* sB = B + (size_t)(n0 + srow) * K + scol;
  char* const myl = lds + (w << 10);

  // A half h = 128 rows (16KB, 2 gloads); B half h = 64 rows (8KB, 1 gload)
  auto STA = [&](int buf, int h, int tt) {
    const bf16* g = sA + ((size_t)(h << 7)) * K + ((size_t)tt << 6);
    char* lb = myl + buf * 49152 + (h << 14);
    gload16(g, lb);
    gload16(g + ((size_t)K << 6), lb + 8192);
  };
  auto STB = [&](int buf, int h, int tt) {
    const bf16* g = sB + ((size_t)(h << 6)) * K + ((size_t)tt << 6);
    gload16(g, myl + buf * 49152 + 32768 + (h << 13));
  };

  const int rdswz = (li << 6) + ((lg << 4) ^ ((li & 8) << 2));

  f32x4 acc[4][4] = {};
  bf16x8 af[2][2], bfr[4][2];

  // prologue: tile0 (6 loads) + tile1 partial (4 loads)
  STB(0, 0, 0); STB(0, 1, 0); STA(0, 0, 0); STA(0, 1, 0);
  if (NT > 1) {
    STB(1, 0, 1); STB(1, 1, 1); STA(1, 0, 1);
    asm volatile("s_waitcnt vmcnt(4)" ::: "memory");
  } else {
    asm volatile("s_waitcnt vmcnt(0)" ::: "memory");
  }
  __builtin_amdgcn_s_barrier();
  __builtin_amdgcn_sched_barrier(0);

  for (int t = 0; t < NT; ++t) {
    const int cur = t & 1;
    const int abase = cur * 49152 + ((wm >> 1) << 14) + ((wm & 1) << 13);
    const int bbase = cur * 49152 + 32768 + (wn << 13);

    // ph1: A frags mi0-1 + B frags ni0-1; stage A_hi(t+1) -> buf cur^1
    N_LDA2(0); N_LDB2(0);
    if (t + 1 < NT) STA((t + 1) & 1, 1, t + 1);
    BAR_WAIT(); N_MMQ(0, 0); BAR_END();

    // ph2: B frags ni2-3; stage B_lo(t+2) -> buf cur
    N_LDB2(2);
    if (t + 2 < NT) STB(cur, 0, t + 2);
    BAR_WAIT(); N_MMQ(0, 1); BAR_END();

    // ph3: A frags mi2-3 (reuse af); stage B_hi(t+2)
    N_LDA2(2);
    if (t + 2 < NT) STB(cur, 1, t + 2);
    BAR_WAIT(); N_MMQ(1, 0); BAR_END();

    // ph4: stage A_lo(t+2); counted vmcnt
    if (t + 2 < NT) STA(cur, 0, t + 2);
    BAR_WAIT(); N_MMQ(1, 1);
    if (t + 2 < NT) { asm volatile("s_waitcnt vmcnt(4)" ::: "memory"); }
    else            { asm volatile("s_waitcnt vmcnt(0)" ::: "memory"); }
    BAR_END();
  }

  // epilogue: row = m0 + wm*64 + mi*16 + lg*4 + r, col = n0 + wn*64 + ni*16 + li
  #pragma unroll
  for (int mi = 0; mi < 4; mi++) {
    const int row = m0 + (wm << 6) + (mi << 4) + (lg << 2);
    #pragma unroll
    for (int ni = 0; ni < 4; ni++) {
      const int col = n0 + (wn << 6) + (ni << 4) + li;
      #pragma unroll
      for (int r2 = 0; r2 < 4; r2++) {
        const size_t idx = (size_t)(row + r2) * N + col;
        float v = acc[mi][ni][r2];
        if (EPI == 0) {
          outb[idx] = (bf16)v;
        } else if (EPI == 1) {
          float s = v + add[idx];
          outf[idx] = s; outb[idx] = (bf16)s;
        } else if (EPI == 2) {
          outb[idx] = (bf16)gelu_t(v + bias[col]);
        } else {
          outf[idx] = v + bias[col] + add[idx];
        }
      }
    }
  }
}

// ---------------- causal flash attention (v2, unchanged) --------------------
__global__ __launch_bounds__(256) void attn_kernel(const bf16* __restrict__ qkv,
                                                   bf16* __restrict__ z)
{
  __shared__ bf16 Ksh[64*64];
  __shared__ bf16 VS[64*64];
  __shared__ bf16 Pl[4*16*64];

  const int tid = threadIdx.x;
  const int w = tid >> 6, l = tid & 63, lg = l >> 4, li = l & 15;
  const int pr = blockIdx.x & 15, bh = blockIdx.x >> 4;
  const int h = bh & 15, b = bh >> 4;
  const size_t tb = (size_t)b * 2048;

  const int srow = tid >> 3, sc = tid & 7;
  const bf16* Kg = qkv + (tb + srow) * 3072 + 1024 + (h << 6) + ((sc ^ (srow & 7)) << 3);
  const bf16* Vg = qkv + (tb + srow) * 3072 + 2048 + (h << 6) + (sc << 3);
  const int vkg0 = (srow >> 3) << 9;
  const int vj   = srow & 7;

  char* pw = (char*)Pl + (w << 11) + li * 128;
  const int psw = (li & 3) << 5;

  for (int hf = 0; hf < 2; ++hf) {
    const int qt = hf ? pr : (31 - pr);
    const int q0 = qt << 6;
    const int qw = q0 + (w << 4);

    const bf16* Qp = qkv + (tb + qw + li) * 3072 + (h << 6);
    bf16x8 qa0 = *(const bf16x8*)(Qp + (lg << 3));
    bf16x8 qa1 = *(const bf16x8*)(Qp + 32 + (lg << 3));
    #pragma unroll
    for (int e = 0; e < 8; e++) {
      qa0[e] = (bf16)((float)qa0[e] * 0.125f);
      qa1[e] = (bf16)((float)qa1[e] * 0.125f);
    }

    f32x4 zacc[4] = {};
    float mR = -1e30f, lS = 0.f;

    const int nkt = qt + 1;
    for (int kt = 0; kt < nkt; ++kt) {
      const int pb = kt << 6;
      const size_t roff = (size_t)pb * 3072;
      __syncthreads();
      gload16(Kg + roff,                   Ksh + (w << 9));
      gload16(Kg + roff + (size_t)32*3072, Ksh + 2048 + (w << 9));
      #pragma unroll
      for (int pass = 0; pass < 2; ++pass) {
        bf16x8 vv = *(const bf16x8*)(Vg + roff + (size_t)pass*32*3072);
        const int kgb = (pass << 11) + vkg0;
        #pragma unroll
        for (int j2 = 0; j2 < 8; j2++) {
          int dd = (sc << 3) + j2;
          VS[kgb + ((dd ^ sc) << 3) + vj] = vv[j2];
        }
      }
      __syncthreads();

      f32x4 s[4];
      #pragma unroll
      for (int sub = 0; sub < 4; ++sub) {
        const char* kr = (const char*)Ksh + ((sub << 4) + li) * 128;
        const int c0 = (lg ^ (li & 7)) << 4;
        bf16x8 kb0 = *(const bf16x8*)(kr + c0);
        bf16x8 kb1 = *(const bf16x8*)(kr + (c0 ^ 64));
        f32x4 a2 = {};
        a2 = MFMA(kb0, qa0, a2);
        a2 = MFMA(kb1, qa1, a2);
        s[sub] = a2;
      }

      if (pb + 63 > qw) {
        #pragma unroll
        for (int sub = 0; sub < 4; ++sub)
          #pragma unroll
          for (int r = 0; r < 4; ++r)
            if (pb + (sub << 4) + (lg << 2) + r > qw + li) s[sub][r] = -1e30f;
      }

      f32x4 m4;
      #pragma unroll
      for (int r = 0; r < 4; ++r)
        m4[r] = fmaxf(fmaxf(s[0][r], s[1][r]), fmaxf(s[2][r], s[3][r]));
      float mx = fmaxf(fmaxf(m4[0], m4[1]), fmaxf(m4[2], m4[3]));
      mx = fmaxf(mx, __shfl_xor(mx, 16));
      mx = fmaxf(mx, __shfl_xor(mx, 32));

      float mn = mR;
      if (!__all(mx <= mR + 8.0f)) {
        mn = fmaxf(mR, mx);
        float c = __expf(mR - mn);
        mR = mn;
        lS *= c;
        float cr0 = __shfl(c, (lg << 2) + 0);
        float cr1 = __shfl(c, (lg << 2) + 1);
        float cr2 = __shfl(c, (lg << 2) + 2);
        float cr3 = __shfl(c, (lg << 2) + 3);
        #pragma unroll
        for (int d = 0; d < 4; ++d) {
          zacc[d][0] *= cr0; zacc[d][1] *= cr1;
          zacc[d][2] *= cr2; zacc[d][3] *= cr3;
        }
      }

      f32x4 p[4];
      #pragma unroll
      for (int sub = 0; sub < 4; ++sub)
        #pragma unroll
        for (int r = 0; r < 4; ++r)
          p[sub][r] = __expf(s[sub][r] - mn);
      f32x4 t4 = p[0] + p[1] + p[2] + p[3];
      float sm = (t4[0] + t4[1]) + (t4[2] + t4[3]);
      sm += __shfl_xor(sm, 16);
      sm += __shfl_xor(sm, 32);
      lS += sm;

      #pragma unroll
      for (int sub = 0; sub < 4; ++sub) {
        bf16x4 pk;
        pk[0] = (bf16)p[sub][0]; pk[1] = (bf16)p[sub][1];
        pk[2] = (bf16)p[sub][2]; pk[3] = (bf16)p[sub][3];
        *(bf16x4*)(pw + (((sub << 5) + (lg << 3)) ^ psw)) = pk;
      }

      #pragma unroll
      for (int kc = 0; kc < 2; ++kc) {
        bf16x8 pa = *(const bf16x8*)(pw + (((kc << 6) + (lg << 4)) ^ psw));
        #pragma unroll
        for (int d = 0; d < 4; ++d) {
          int dd = (d << 4) + li;
          int f = dd ^ ((dd >> 3) & 7);
          bf16x8 vb = *(const bf16x8*)(VS + (((kc << 2) + lg) << 9) + (f << 3));
          zacc[d] = MFMA(pa, vb, zacc[d]);
        }
      }
    }

    float rls[4];
    #pragma unroll
    for (int r = 0; r < 4; ++r) rls[r] = 1.0f / __shfl(lS, (lg << 2) + r);
    bf16* zp = z + (tb + qw) * 1024 + (h << 6);
    #pragma unroll
    for (int d = 0; d < 4; ++d)
      #pragma unroll
      for (int r = 0; r < 4; ++r)
        zp[(size_t)((lg << 2) + r) * 1024 + (d << 4) + li] = (bf16)(zacc[d][r] * rls[r]);
  }
}

// ---------------- launch ----------------------------------------------------
extern "C" void kernel_launch(void* const* d_in, const int* in_sizes, int n_in,
                              void* d_out, int out_size, void* d_ws, size_t ws_size,
                              hipStream_t stream)
{
  const float* x     = (const float*)d_in[0];
  const float* W_K   = (const float*)d_in[1];
  const float* W_Q   = (const float*)d_in[2];
  const float* W_V   = (const float*)d_in[3];
  const float* W_O   = (const float*)d_in[4];
  const float* W_in  = (const float*)d_in[5];
  const float* b_in  = (const float*)d_in[6];
  const float* W_out = (const float*)d_in[7];
  const float* b_out = (const float*)d_in[8];
  float* out = (float*)d_out;

  char* ws = (char*)d_ws;
  bf16*  xb   = (bf16*)ws;  ws += (size_t)8192*1024*2;
  bf16*  wqkv = (bf16*)ws;  ws += (size_t)3072*1024*2;
  bf16*  wo   = (bf16*)ws;  ws += (size_t)1024*1024*2;
  bf16*  win  = (bf16*)ws;  ws += (size_t)4096*1024*2;
  bf16*  wout = (bf16*)ws;  ws += (size_t)1024*4096*2;
  bf16*  qkv  = (bf16*)ws;  ws += (size_t)8192*3072*2;
  bf16*  zb   = (bf16*)ws;  ws += (size_t)8192*1024*2;
  float* x1f  = (float*)ws; ws += (size_t)8192*1024*4;
  bf16*  x1b  = (bf16*)ws;  ws += (size_t)8192*1024*2;
  bf16*  hb   = (bf16*)ws;  // 8192*4096*2

  auto cast = [&](const float* src, bf16* dst, size_t n) {
    int n8 = (int)(n / 8);
    cast_kernel<<<dim3((n8 + 255) / 256), dim3(256), 0, stream>>>(src, dst, n8);
  };
  cast(x,     xb,               (size_t)8192*1024);
  cast(W_Q,   wqkv,             (size_t)1024*1024);
  cast(W_K,   wqkv + 1024*1024, (size_t)1024*1024);
  cast(W_V,   wqkv + 2048*1024, (size_t)1024*1024);
  cast(W_O,   wo,               (size_t)1024*1024);
  cast(W_in,  win,              (size_t)4096*1024);
  cast(W_out, wout,             (size_t)1024*4096);

  // QKV = x @ Wqkv^T    [8192 x 3072]  (8-phase 256^2, 384 blocks)
  gemm256<0><<<dim3(384), 512, 0, stream>>>(xb, wqkv, nullptr, qkv, nullptr, nullptr, 8192, 3072, 1024, 12);
  // causal attention -> z [8192 x 1024]
  attn_kernel<<<dim3(1024), 256, 0, stream>>>(qkv, zb);
  // x1 = x + z @ W_O^T   (8-phase 256x128, 256 blocks = full chip)
  gemm128n<1><<<dim3(256), 512, 0, stream>>>(zb, wo, x1f, x1b, x, nullptr, 8192, 1024, 1024, 8);
  // h = gelu(x1 @ W_in^T + b_in)  (8-phase 256^2, 512 blocks)
  gemm256<2><<<dim3(512), 512, 0, stream>>>(x1b, win, nullptr, hb, nullptr, b_in, 8192, 4096, 1024, 16);
  // out = x1 + h @ W_out^T + b_out  (8-phase 256x128, K=4096, 256 blocks)
  gemm128n<3><<<dim3(256), 512, 0, stream>>>(hb, wout, out, nullptr, x1f, b_out, 8192, 1024, 4096, 8);
}

// Round 6
// 372.191 us; speedup vs baseline: 1.8201x; 1.0250x over previous
//
#include <hip/hip_runtime.h>
#include <hip/hip_bf16.h>

typedef __bf16 bf16;
typedef __bf16 bf16x8 __attribute__((ext_vector_type(8)));
typedef __bf16 bf16x4 __attribute__((ext_vector_type(4)));
typedef float  f32x4  __attribute__((ext_vector_type(4)));

#define MFMA(a,b,c) __builtin_amdgcn_mfma_f32_16x16x32_bf16(a,b,c,0,0,0)
#define EXP2F(x) __builtin_amdgcn_exp2f(x)

__device__ __forceinline__ void gload16(const void* g, void* l) {
  __builtin_amdgcn_global_load_lds((__attribute__((address_space(1))) void*)(g),
                                   (__attribute__((address_space(3))) void*)(l), 16, 0, 0);
}

// ---------------- fp32 -> bf16 cast ----------------
__global__ void cast_kernel(const float* __restrict__ in, bf16* __restrict__ out, int n8) {
  int i = blockIdx.x * 256 + threadIdx.x;
  if (i >= n8) return;
  const float4* p = (const float4*)in;
  float4 a = p[2*i], b = p[2*i+1];
  bf16x8 v;
  v[0]=(bf16)a.x; v[1]=(bf16)a.y; v[2]=(bf16)a.z; v[3]=(bf16)a.w;
  v[4]=(bf16)b.x; v[5]=(bf16)b.y; v[6]=(bf16)b.z; v[7]=(bf16)b.w;
  *(bf16x8*)(out + (size_t)8*i) = v;
}

__device__ __forceinline__ float gelu_t(float s) {
  float u = s * (0.7978845608f + 0.0356774081f * s * s);
  return s / (1.0f + __expf(-2.0f * u));
}

#define BAR_WAIT() { __builtin_amdgcn_s_barrier(); \
                     asm volatile("s_waitcnt lgkmcnt(0)" ::: "memory"); \
                     __builtin_amdgcn_sched_barrier(0); }
#define BAR_END()  { __builtin_amdgcn_s_barrier(); \
                     __builtin_amdgcn_sched_barrier(0); }

// ============ 256x256 8-phase GEMM (m201 template), C = A @ B^T =============
#define LDA_PH(MI2) { _Pragma("unroll") for (int i = 0; i < 4; i++) { \
    af[i][0] = *(const bf16x8*)(lds + ab + ((((MI2)<<2)+i) << 11) + rdswz); \
    af[i][1] = *(const bf16x8*)(lds + ab + ((((MI2)<<2)+i) << 11) + 1024 + rdswz); } }

#define LDB_PH(NI2) { _Pragma("unroll") for (int n = 0; n < 2; n++) { \
    bfr[((NI2)<<1)+n][0] = *(const bf16x8*)(lds + bb + (((((NI2)<<1)+n)) << 11) + rdswz); \
    bfr[((NI2)<<1)+n][1] = *(const bf16x8*)(lds + bb + (((((NI2)<<1)+n)) << 11) + 1024 + rdswz); } }

#define MM_PH(MI2, NI2) { __builtin_amdgcn_s_setprio(1); \
    _Pragma("unroll") for (int i = 0; i < 4; i++) \
      _Pragma("unroll") for (int n = 0; n < 2; n++) { \
        acc[((MI2)<<2)+i][((NI2)<<1)+n] = MFMA(af[i][0], bfr[((NI2)<<1)+n][0], acc[((MI2)<<2)+i][((NI2)<<1)+n]); \
        acc[((MI2)<<2)+i][((NI2)<<1)+n] = MFMA(af[i][1], bfr[((NI2)<<1)+n][1], acc[((MI2)<<2)+i][((NI2)<<1)+n]); } \
    __builtin_amdgcn_s_setprio(0); }

template<int EPI>
__global__ __launch_bounds__(512, 2) void gemm256(
    const bf16* __restrict__ A, const bf16* __restrict__ B,
    float* __restrict__ outf, bf16* __restrict__ outb,
    const float* __restrict__ add, const float* __restrict__ bias,
    bf16* __restrict__ vtb,
    int M, int N, int K, int gx)
{
  __shared__ __attribute__((aligned(128))) char lds[131072];
  const int tid = threadIdx.x;
  const int w = tid >> 6, l = tid & 63, lg = l >> 4, li = l & 15;
  const int wm = w >> 2, wn = w & 3;

  const int nwg = gridDim.x, orig = blockIdx.x;
  const int q = nwg >> 3, r = nwg & 7;
  const int xcd = orig & 7, pos = orig >> 3;
  const int wg = (xcd < r ? xcd*(q+1) : r*(q+1) + (xcd-r)*q) + pos;
  const int m0 = (wg / gx) << 8, n0 = (wg % gx) << 8;

  const int NT = K >> 6;

  const int srow = ((tid >> 7) << 4) + ((tid >> 2) & 15);
  const int scol = (((tid >> 6) & 1) << 5) + (((tid & 3) << 3) ^ (((tid >> 5) & 1) << 4));
  const bf16* sA = A + (size_t)(m0 + srow) * K + scol;
  const bf16* sB = B + (size_t)(n0 + srow) * K + scol;
  char* const myl = lds + (w << 10);

  auto STG = [&](const bf16* s0, int buf, int isB, int h, int tt) {
    const bf16* g = s0 + ((size_t)(h << 7)) * K + ((size_t)tt << 6);
    char* lb = myl + (buf << 16) + (isB << 15) + (h << 14);
    gload16(g, lb);
    gload16(g + ((size_t)K << 6), lb + 8192);
  };

  const int rdswz = (li << 6) + ((lg << 4) ^ ((li & 8) << 2));

  f32x4 acc[8][4] = {};
  bf16x8 af[4][2], bfr[4][2];

  STG(sB, 0, 1, 0, 0); STG(sB, 0, 1, 1, 0); STG(sA, 0, 0, 0, 0); STG(sA, 0, 0, 1, 0);
  asm volatile("s_waitcnt vmcnt(4)" ::: "memory");
  if (NT > 1) {
    STG(sB, 1, 1, 0, 1); STG(sB, 1, 1, 1, 1); STG(sA, 1, 0, 0, 1);
    asm volatile("s_waitcnt vmcnt(6)" ::: "memory");
  } else {
    asm volatile("s_waitcnt vmcnt(0)" ::: "memory");
  }
  __builtin_amdgcn_s_barrier();
  __builtin_amdgcn_sched_barrier(0);

  for (int t = 0; t < NT; ++t) {
    const int cur = t & 1;
    const int ab = (cur << 16) + (wm << 14);
    const int bb = (cur << 16) + 32768 + (wn << 13);

    LDA_PH(0); LDB_PH(0);
    if (t + 1 < NT) STG(sA, (t + 1) & 1, 0, 1, t + 1);
    BAR_WAIT(); MM_PH(0, 0); BAR_END();

    LDB_PH(1);
    if (t + 2 < NT) STG(sB, cur, 1, 0, t + 2);
    BAR_WAIT(); MM_PH(0, 1); BAR_END();

    LDA_PH(1);
    if (t + 2 < NT) STG(sB, cur, 1, 1, t + 2);
    BAR_WAIT(); MM_PH(1, 0); BAR_END();

    if (t + 2 < NT) STG(sA, cur, 0, 0, t + 2);
    BAR_WAIT(); MM_PH(1, 1);
    if (t + 2 < NT) { asm volatile("s_waitcnt vmcnt(6)" ::: "memory"); }
    else            { asm volatile("s_waitcnt vmcnt(0)" ::: "memory"); }
    BAR_END();
  }

  // V-blocks of the QKV GEMM: write transposed into vt[bh][dd][p]
  if (EPI == 0 && n0 >= 2048) {
    #pragma unroll
    for (int mi = 0; mi < 8; mi++) {
      const int row = m0 + (wm << 7) + (mi << 4) + (lg << 2);
      const int p = row & 2047;
      const size_t bhb = (size_t)((row >> 11) << 4);
      #pragma unroll
      for (int ni = 0; ni < 4; ni++) {
        const int col = n0 + (wn << 6) + (ni << 4) + li;
        const int hh = (col >> 6) & 15, dd = col & 63;
        bf16x4 pk;
        pk[0] = (bf16)acc[mi][ni][0]; pk[1] = (bf16)acc[mi][ni][1];
        pk[2] = (bf16)acc[mi][ni][2]; pk[3] = (bf16)acc[mi][ni][3];
        *(bf16x4*)(vtb + ((bhb + hh) * 64 + dd) * 2048 + p) = pk;
      }
    }
    return;
  }

  #pragma unroll
  for (int mi = 0; mi < 8; mi++) {
    const int row = m0 + (wm << 7) + (mi << 4) + (lg << 2);
    #pragma unroll
    for (int ni = 0; ni < 4; ni++) {
      const int col = n0 + (wn << 6) + (ni << 4) + li;
      #pragma unroll
      for (int r2 = 0; r2 < 4; r2++) {
        const size_t idx = (size_t)(row + r2) * N + col;
        float v = acc[mi][ni][r2];
        if (EPI == 0) {
          outb[idx] = (bf16)v;
        } else if (EPI == 1) {
          float s = v + add[idx];
          outf[idx] = s; outb[idx] = (bf16)s;
        } else if (EPI == 2) {
          outb[idx] = (bf16)gelu_t(v + bias[col]);
        } else {
          outf[idx] = v + bias[col] + add[idx];
        }
      }
    }
  }
}

// ============ 256x128 8-phase GEMM, C = A @ B^T ==============================
#define N_LDA2(BMI) { _Pragma("unroll") for (int i = 0; i < 2; i++) { \
    af[i][0] = *(const bf16x8*)(lds + abase + (((BMI)+i) << 11) + rdswz); \
    af[i][1] = *(const bf16x8*)(lds + abase + (((BMI)+i) << 11) + 1024 + rdswz); } }

#define N_LDB2(BNI) { _Pragma("unroll") for (int n = 0; n < 2; n++) { \
    bfr[(BNI)+n][0] = *(const bf16x8*)(lds + bbase + (((BNI)+n) << 11) + rdswz); \
    bfr[(BNI)+n][1] = *(const bf16x8*)(lds + bbase + (((BNI)+n) << 11) + 1024 + rdswz); } }

#define N_MMQ(MB, NB) { __builtin_amdgcn_s_setprio(1); \
    _Pragma("unroll") for (int i = 0; i < 2; i++) \
      _Pragma("unroll") for (int n = 0; n < 2; n++) { \
        acc[((MB)<<1)+i][((NB)<<1)+n] = MFMA(af[i][0], bfr[((NB)<<1)+n][0], acc[((MB)<<1)+i][((NB)<<1)+n]); \
        acc[((MB)<<1)+i][((NB)<<1)+n] = MFMA(af[i][1], bfr[((NB)<<1)+n][1], acc[((MB)<<1)+i][((NB)<<1)+n]); } \
    __builtin_amdgcn_s_setprio(0); }

template<int EPI>
__global__ __launch_bounds__(512, 2) void gemm128n(
    const bf16* __restrict__ A, const bf16* __restrict__ B,
    float* __restrict__ outf, bf16* __restrict__ outb,
    const float* __restrict__ add, const float* __restrict__ bias,
    int M, int N, int K, int gx)
{
  __shared__ __attribute__((aligned(128))) char lds[98304];
  const int tid = threadIdx.x;
  const int w = tid >> 6, l = tid & 63, lg = l >> 4, li = l & 15;
  const int wm = w >> 1, wn = w & 1;

  const int nwg = gridDim.x, orig = blockIdx.x;
  const int q = nwg >> 3, r = nwg & 7;
  const int xcd = orig & 7, pos = orig >> 3;
  const int wg = (xcd < r ? xcd*(q+1) : r*(q+1) + (xcd-r)*q) + pos;
  const int m0 = (wg / gx) << 8, n0 = (wg % gx) << 7;

  const int NT = K >> 6;

  const int srow = ((tid >> 7) << 4) + ((tid >> 2) & 15);
  const int scol = (((tid >> 6) & 1) << 5) + (((tid & 3) << 3) ^ (((tid >> 5) & 1) << 4));
  const bf16* sA = A + (size_t)(m0 + srow) * K + scol;
  const bf16* sB = B + (size_t)(n0 + srow) * K + scol;
  char* const myl = lds + (w << 10);

  auto STA = [&](int buf, int h, int tt) {
    const bf16* g = sA + ((size_t)(h << 7)) * K + ((size_t)tt << 6);
    char* lb = myl + buf * 49152 + (h << 14);
    gload16(g, lb);
    gload16(g + ((size_t)K << 6), lb + 8192);
  };
  auto STB = [&](int buf, int h, int tt) {
    const bf16* g = sB + ((size_t)(h << 6)) * K + ((size_t)tt << 6);
    gload16(g, myl + buf * 49152 + 32768 + (h << 13));
  };

  const int rdswz = (li << 6) + ((lg << 4) ^ ((li & 8) << 2));

  f32x4 acc[4][4] = {};
  bf16x8 af[2][2], bfr[4][2];

  STB(0, 0, 0); STB(0, 1, 0); STA(0, 0, 0); STA(0, 1, 0);
  if (NT > 1) {
    STB(1, 0, 1); STB(1, 1, 1); STA(1, 0, 1);
    asm volatile("s_waitcnt vmcnt(4)" ::: "memory");
  } else {
    asm volatile("s_waitcnt vmcnt(0)" ::: "memory");
  }
  __builtin_amdgcn_s_barrier();
  __builtin_amdgcn_sched_barrier(0);

  for (int t = 0; t < NT; ++t) {
    const int cur = t & 1;
    const int abase = cur * 49152 + ((wm >> 1) << 14) + ((wm & 1) << 13);
    const int bbase = cur * 49152 + 32768 + (wn << 13);

    N_LDA2(0); N_LDB2(0);
    if (t + 1 < NT) STA((t + 1) & 1, 1, t + 1);
    BAR_WAIT(); N_MMQ(0, 0); BAR_END();

    N_LDB2(2);
    if (t + 2 < NT) STB(cur, 0, t + 2);
    BAR_WAIT(); N_MMQ(0, 1); BAR_END();

    N_LDA2(2);
    if (t + 2 < NT) STB(cur, 1, t + 2);
    BAR_WAIT(); N_MMQ(1, 0); BAR_END();

    if (t + 2 < NT) STA(cur, 0, t + 2);
    BAR_WAIT(); N_MMQ(1, 1);
    if (t + 2 < NT) { asm volatile("s_waitcnt vmcnt(4)" ::: "memory"); }
    else            { asm volatile("s_waitcnt vmcnt(0)" ::: "memory"); }
    BAR_END();
  }

  #pragma unroll
  for (int mi = 0; mi < 4; mi++) {
    const int row = m0 + (wm << 6) + (mi << 4) + (lg << 2);
    #pragma unroll
    for (int ni = 0; ni < 4; ni++) {
      const int col = n0 + (wn << 6) + (ni << 4) + li;
      #pragma unroll
      for (int r2 = 0; r2 < 4; r2++) {
        const size_t idx = (size_t)(row + r2) * N + col;
        float v = acc[mi][ni][r2];
        if (EPI == 0) {
          outb[idx] = (bf16)v;
        } else if (EPI == 1) {
          float s = v + add[idx];
          outf[idx] = s; outb[idx] = (bf16)s;
        } else if (EPI == 2) {
          outb[idx] = (bf16)gelu_t(v + bias[col]);
        } else {
          outf[idx] = v + bias[col] + add[idx];
        }
      }
    }
  }
}

// ---------------- causal flash attention (v3) --------------------------------
// Double-buffered K and V^T staging (pure gload16, pre-XOR swizzled source),
// exp2-domain softmax, paired q-tiles for balance. V comes pre-transposed in
// vt[bh][dd=64][p=2048] (written by the QKV GEMM's V-block epilogue).
__global__ __launch_bounds__(256) void attn_kernel(const bf16* __restrict__ qkv,
                                                   const bf16* __restrict__ vt,
                                                   bf16* __restrict__ z)
{
  __shared__ bf16 Ksh[2][64*64];   // [p][dd], slot c of row holds chunk c^(row&7)
  __shared__ bf16 Vsh[2][64*64];   // [dd][p], same swizzle
  __shared__ bf16 Pl[4*16*64];     // per-wave P tile

  const int tid = threadIdx.x;
  const int w = tid >> 6, l = tid & 63, lg = l >> 4, li = l & 15;
  const int pr = blockIdx.x & 15, bh = blockIdx.x >> 4;
  const int h = bh & 15, b = bh >> 4;
  const size_t tb = (size_t)b * 2048;

  const int srow = tid >> 3, sc = tid & 7;
  const bf16* Kg = qkv + (tb + srow) * 3072 + 1024 + (h << 6) + ((sc ^ (srow & 7)) << 3);
  const bf16* Vg = vt + ((size_t)bh * 64 + srow) * 2048 + ((sc ^ (srow & 7)) << 3);

  char* pw = (char*)Pl + (w << 11) + li * 128;
  const int psw = (li & 3) << 5;

  for (int hf = 0; hf < 2; ++hf) {
    const int qt = hf ? pr : (31 - pr);          // heavy tile first
    const int qw = (qt << 6) + (w << 4);

    const bf16* Qp = qkv + (tb + qw + li) * 3072 + (h << 6);
    bf16x8 qa0 = *(const bf16x8*)(Qp + (lg << 3));
    bf16x8 qa1 = *(const bf16x8*)(Qp + 32 + (lg << 3));
    #pragma unroll
    for (int e = 0; e < 8; e++) {
      qa0[e] = (bf16)((float)qa0[e] * 0.1803368801f);   // (1/8)*log2(e)
      qa1[e] = (bf16)((float)qa1[e] * 0.1803368801f);
    }

    f32x4 zacc[4] = {};
    float mR = -1e30f, lS = 0.f;
    const int nkt = qt + 1;

    // prologue: stage tile 0 -> buf 0
    gload16(Kg,                   (bf16*)Ksh[0] + (w << 9));
    gload16(Kg + (size_t)32*3072, (bf16*)Ksh[0] + 2048 + (w << 9));
    gload16(Vg,                   (bf16*)Vsh[0] + (w << 9));
    gload16(Vg + (size_t)32*2048, (bf16*)Vsh[0] + 2048 + (w << 9));
    __syncthreads();

    for (int kt = 0; kt < nkt; ++kt) {
      const int cur = kt & 1;
      const int pb = kt << 6;

      if (kt + 1 < nkt) {   // stage next tile into other buffer (async)
        const int nb = cur ^ 1;
        const size_t ko = (size_t)(pb + 64) * 3072;
        gload16(Kg + ko,                   (bf16*)Ksh[nb] + (w << 9));
        gload16(Kg + ko + (size_t)32*3072, (bf16*)Ksh[nb] + 2048 + (w << 9));
        gload16(Vg + pb + 64,                   (bf16*)Vsh[nb] + (w << 9));
        gload16(Vg + pb + 64 + (size_t)32*2048, (bf16*)Vsh[nb] + 2048 + (w << 9));
      }

      // S^T = K Q^T : C col = q (li), C row = key-in-16 (lg*4+r), sub = key/16
      f32x4 s[4];
      __builtin_amdgcn_s_setprio(1);
      #pragma unroll
      for (int sub = 0; sub < 4; ++sub) {
        const char* kr = (const char*)Ksh[cur] + ((sub << 4) + li) * 128;
        const int c0 = (lg ^ (li & 7)) << 4;
        bf16x8 kb0 = *(const bf16x8*)(kr + c0);
        bf16x8 kb1 = *(const bf16x8*)(kr + (c0 ^ 64));
        f32x4 a2 = {};
        a2 = MFMA(kb0, qa0, a2);
        a2 = MFMA(kb1, qa1, a2);
        s[sub] = a2;
      }
      __builtin_amdgcn_s_setprio(0);

      // causal mask (diagonal tile only)
      if (pb + 63 > qw) {
        #pragma unroll
        for (int sub = 0; sub < 4; ++sub)
          #pragma unroll
          for (int r = 0; r < 4; ++r)
            if (pb + (sub << 4) + (lg << 2) + r > qw + li) s[sub][r] = -1e30f;
      }

      // online softmax in log2 domain
      f32x4 m4;
      #pragma unroll
      for (int r = 0; r < 4; ++r)
        m4[r] = fmaxf(fmaxf(s[0][r], s[1][r]), fmaxf(s[2][r], s[3][r]));
      float mx = fmaxf(fmaxf(m4[0], m4[1]), fmaxf(m4[2], m4[3]));
      mx = fmaxf(mx, __shfl_xor(mx, 16));
      mx = fmaxf(mx, __shfl_xor(mx, 32));

      float mn = mR;
      if (!__all(mx <= mR + 11.5f)) {          // defer-max, THR = 8*log2e
        mn = fmaxf(mR, mx);
        float c = EXP2F(mR - mn);
        mR = mn;
        lS *= c;
        float cr0 = __shfl(c, (lg << 2) + 0);
        float cr1 = __shfl(c, (lg << 2) + 1);
        float cr2 = __shfl(c, (lg << 2) + 2);
        float cr3 = __shfl(c, (lg << 2) + 3);
        #pragma unroll
        for (int d = 0; d < 4; ++d) {
          zacc[d][0] *= cr0; zacc[d][1] *= cr1;
          zacc[d][2] *= cr2; zacc[d][3] *= cr3;
        }
      }

      f32x4 p[4];
      #pragma unroll
      for (int sub = 0; sub < 4; ++sub)
        #pragma unroll
        for (int r = 0; r < 4; ++r)
          p[sub][r] = EXP2F(s[sub][r] - mn);
      f32x4 t4 = p[0] + p[1] + p[2] + p[3];
      lS += (t4[0] + t4[1]) + (t4[2] + t4[3]);   // partial (per lg-group); reduced at end

      // pack P -> swizzled wave-private LDS
      #pragma unroll
      for (int sub = 0; sub < 4; ++sub) {
        bf16x4 pk;
        pk[0] = (bf16)p[sub][0]; pk[1] = (bf16)p[sub][1];
        pk[2] = (bf16)p[sub][2]; pk[3] = (bf16)p[sub][3];
        *(bf16x4*)(pw + (((sub << 5) + (lg << 3)) ^ psw)) = pk;
      }

      // PV: pa = P[q=li][keys kc*32+lg*8..], vb = V^T[dd=d*16+li][same keys]
      __builtin_amdgcn_s_setprio(1);
      #pragma unroll
      for (int kc = 0; kc < 2; ++kc) {
        bf16x8 pa = *(const bf16x8*)(pw + (((kc << 6) + (lg << 4)) ^ psw));
        #pragma unroll
        for (int d = 0; d < 4; ++d) {
          const char* vr = (const char*)Vsh[cur] + ((d << 4) + li) * 128;
          bf16x8 vb = *(const bf16x8*)(vr + ((((kc << 2) + lg) ^ (li & 7)) << 4));
          zacc[d] = MFMA(pa, vb, zacc[d]);
        }
      }
      __builtin_amdgcn_s_setprio(0);

      __syncthreads();   // drains this wave's staging gloads; syncs buffers
    }

    // finish row-sum reduction (rescales were row-uniform)
    lS += __shfl_xor(lS, 16);
    lS += __shfl_xor(lS, 32);

    float rls[4];
    #pragma unroll
    for (int r = 0; r < 4; ++r) rls[r] = 1.0f / __shfl(lS, (lg << 2) + r);
    bf16* zp = z + (tb + qw) * 1024 + (h << 6);
    #pragma unroll
    for (int d = 0; d < 4; ++d)
      #pragma unroll
      for (int r = 0; r < 4; ++r)
        zp[(size_t)((lg << 2) + r) * 1024 + (d << 4) + li] = (bf16)(zacc[d][r] * rls[r]);
  }
}

// ---------------- launch ----------------------------------------------------
extern "C" void kernel_launch(void* const* d_in, const int* in_sizes, int n_in,
                              void* d_out, int out_size, void* d_ws, size_t ws_size,
                              hipStream_t stream)
{
  const float* x     = (const float*)d_in[0];
  const float* W_K   = (const float*)d_in[1];
  const float* W_Q   = (const float*)d_in[2];
  const float* W_V   = (const float*)d_in[3];
  const float* W_O   = (const float*)d_in[4];
  const float* W_in  = (const float*)d_in[5];
  const float* b_in  = (const float*)d_in[6];
  const float* W_out = (const float*)d_in[7];
  const float* b_out = (const float*)d_in[8];
  float* out = (float*)d_out;

  char* ws = (char*)d_ws;
  bf16*  xb   = (bf16*)ws;  ws += (size_t)8192*1024*2;
  bf16*  wqkv = (bf16*)ws;  ws += (size_t)3072*1024*2;
  bf16*  wo   = (bf16*)ws;  ws += (size_t)1024*1024*2;
  bf16*  win  = (bf16*)ws;  ws += (size_t)4096*1024*2;
  bf16*  wout = (bf16*)ws;  ws += (size_t)1024*4096*2;
  bf16*  qkv  = (bf16*)ws;  ws += (size_t)8192*3072*2;
  bf16*  zb   = (bf16*)ws;  ws += (size_t)8192*1024*2;
  float* x1f  = (float*)ws; ws += (size_t)8192*1024*4;
  bf16*  x1b  = (bf16*)ws;  ws += (size_t)8192*1024*2;
  bf16*  hb   = (bf16*)ws;  // 8192*4096*2
  bf16*  vtb  = hb;         // alias: vt[64][64][2048] (16.8MB) used before MLP1 writes hb

  auto cast = [&](const float* src, bf16* dst, size_t n) {
    int n8 = (int)(n / 8);
    cast_kernel<<<dim3((n8 + 255) / 256), dim3(256), 0, stream>>>(src, dst, n8);
  };
  cast(x,     xb,               (size_t)8192*1024);
  cast(W_Q,   wqkv,             (size_t)1024*1024);
  cast(W_K,   wqkv + 1024*1024, (size_t)1024*1024);
  cast(W_V,   wqkv + 2048*1024, (size_t)1024*1024);
  cast(W_O,   wo,               (size_t)1024*1024);
  cast(W_in,  win,              (size_t)4096*1024);
  cast(W_out, wout,             (size_t)1024*4096);

  // QKV = x @ Wqkv^T  [8192 x 3072]; V-blocks land transposed in vtb
  gemm256<0><<<dim3(384), 512, 0, stream>>>(xb, wqkv, nullptr, qkv, nullptr, nullptr, vtb, 8192, 3072, 1024, 12);
  // causal attention -> z [8192 x 1024]
  attn_kernel<<<dim3(1024), 256, 0, stream>>>(qkv, vtb, zb);
  // x1 = x + z @ W_O^T   (256x128, 256 blocks)
  gemm128n<1><<<dim3(256), 512, 0, stream>>>(zb, wo, x1f, x1b, x, nullptr, 8192, 1024, 1024, 8);
  // h = gelu(x1 @ W_in^T + b_in)  (256^2, 512 blocks)
  gemm256<2><<<dim3(512), 512, 0, stream>>>(x1b, win, nullptr, hb, nullptr, b_in, nullptr, 8192, 4096, 1024, 16);
  // out = x1 + h @ W_out^T + b_out  (256x128, K=4096, 256 blocks)
  gemm128n<3><<<dim3(256), 512, 0, stream>>>(hb, wout, out, nullptr, x1f, b_out, 8192, 1024, 4096, 8);
}

// Round 7
// 334.952 us; speedup vs baseline: 2.0225x; 1.1112x over previous
//
#include <hip/hip_runtime.h>
#include <hip/hip_bf16.h>

typedef __bf16 bf16;
typedef __bf16 bf16x8 __attribute__((ext_vector_type(8)));
typedef __bf16 bf16x4 __attribute__((ext_vector_type(4)));
typedef float  f32x4  __attribute__((ext_vector_type(4)));

#define MFMA(a,b,c) __builtin_amdgcn_mfma_f32_16x16x32_bf16(a,b,c,0,0,0)
#define EXP2F(x) __builtin_amdgcn_exp2f(x)

__device__ __forceinline__ void gload16(const void* g, void* l) {
  __builtin_amdgcn_global_load_lds((__attribute__((address_space(1))) void*)(g),
                                   (__attribute__((address_space(3))) void*)(l), 16, 0, 0);
}

// ---------------- fp32 -> bf16 cast ----------------
__global__ void cast_kernel(const float* __restrict__ in, bf16* __restrict__ out, int n8) {
  int i = blockIdx.x * 256 + threadIdx.x;
  if (i >= n8) return;
  const float4* p = (const float4*)in;
  float4 a = p[2*i], b = p[2*i+1];
  bf16x8 v;
  v[0]=(bf16)a.x; v[1]=(bf16)a.y; v[2]=(bf16)a.z; v[3]=(bf16)a.w;
  v[4]=(bf16)b.x; v[5]=(bf16)b.y; v[6]=(bf16)b.z; v[7]=(bf16)b.w;
  *(bf16x8*)(out + (size_t)8*i) = v;
}

__device__ __forceinline__ float gelu_t(float s) {
  float u = s * (0.7978845608f + 0.0356774081f * s * s);
  return s / (1.0f + EXP2F(-2.885390082f * u));   // exp(-2u) = exp2(-2u*log2e)
}

#define LGKM0_FENCE() { asm volatile("s_waitcnt lgkmcnt(0)" ::: "memory"); \
                        __builtin_amdgcn_sched_barrier(0); }

// ============ 256x256 8-phase GEMM (m201 template, merged barriers) =========
// A:[M][K] bf16, B:[N][K] bf16. 512 thr = 8 waves (2M x 4N), BK=64, LDS 128KB.
#define LDA_PH(MI2) { _Pragma("unroll") for (int i = 0; i < 4; i++) { \
    af[i][0] = *(const bf16x8*)(lds + ab + ((((MI2)<<2)+i) << 11) + rdswz); \
    af[i][1] = *(const bf16x8*)(lds + ab + ((((MI2)<<2)+i) << 11) + 1024 + rdswz); } }

#define LDB_PH(NI2) { _Pragma("unroll") for (int n = 0; n < 2; n++) { \
    bfr[((NI2)<<1)+n][0] = *(const bf16x8*)(lds + bb + (((((NI2)<<1)+n)) << 11) + rdswz); \
    bfr[((NI2)<<1)+n][1] = *(const bf16x8*)(lds + bb + (((((NI2)<<1)+n)) << 11) + 1024 + rdswz); } }

#define MM_PH(MI2, NI2) { __builtin_amdgcn_s_setprio(1); \
    _Pragma("unroll") for (int i = 0; i < 4; i++) \
      _Pragma("unroll") for (int n = 0; n < 2; n++) { \
        acc[((MI2)<<2)+i][((NI2)<<1)+n] = MFMA(af[i][0], bfr[((NI2)<<1)+n][0], acc[((MI2)<<2)+i][((NI2)<<1)+n]); \
        acc[((MI2)<<2)+i][((NI2)<<1)+n] = MFMA(af[i][1], bfr[((NI2)<<1)+n][1], acc[((MI2)<<2)+i][((NI2)<<1)+n]); } \
    __builtin_amdgcn_s_setprio(0); }

// One K-tile: 4 phase-start barriers, stage interleaved, single vmcnt at end.
#define GTILE(CUR, S1, S2, VM) { \
    const int ab = ((CUR) << 16) + (wm << 14); \
    const int bb = ((CUR) << 16) + 32768 + (wn << 13); \
    LDA_PH(0); LDB_PH(0); \
    if (S1) STG(sA, (CUR)^1, 0, 1, t + 1); \
    asm volatile("s_waitcnt lgkmcnt(8)" ::: "memory"); \
    __builtin_amdgcn_s_barrier(); LGKM0_FENCE(); \
    MM_PH(0, 0); \
    LDB_PH(1); \
    if (S2) STG(sB, (CUR), 1, 0, t + 2); \
    __builtin_amdgcn_s_barrier(); LGKM0_FENCE(); \
    MM_PH(0, 1); \
    LDA_PH(1); \
    if (S2) STG(sB, (CUR), 1, 1, t + 2); \
    __builtin_amdgcn_s_barrier(); LGKM0_FENCE(); \
    MM_PH(1, 0); \
    if (S2) STG(sA, (CUR), 0, 0, t + 2); \
    MM_PH(1, 1); \
    asm volatile("s_waitcnt vmcnt(" #VM ")" ::: "memory"); \
    __builtin_amdgcn_s_barrier(); \
    __builtin_amdgcn_sched_barrier(0); }

template<int EPI>
__global__ __launch_bounds__(512, 2) void gemm256(
    const bf16* __restrict__ A, const bf16* __restrict__ B,
    float* __restrict__ outf, bf16* __restrict__ outb,
    const float* __restrict__ add, const float* __restrict__ bias,
    bf16* __restrict__ vtb,
    int M, int N, int K, int gx)
{
  __shared__ __attribute__((aligned(128))) char lds[131072];
  const int tid = threadIdx.x;
  const int w = tid >> 6, l = tid & 63, lg = l >> 4, li = l & 15;
  const int wm = w >> 2, wn = w & 3;

  const int nwg = gridDim.x, orig = blockIdx.x;
  const int q = nwg >> 3, r = nwg & 7;
  const int xcd = orig & 7, pos = orig >> 3;
  const int wg = (xcd < r ? xcd*(q+1) : r*(q+1) + (xcd-r)*q) + pos;
  const int m0 = (wg / gx) << 8, n0 = (wg % gx) << 8;

  const int NT = K >> 6;   // NT must be even (K multiple of 128)

  const int srow = ((tid >> 7) << 4) + ((tid >> 2) & 15);
  const int scol = (((tid >> 6) & 1) << 5) + (((tid & 3) << 3) ^ (((tid >> 5) & 1) << 4));
  const bf16* sA = A + (size_t)(m0 + srow) * K + scol;
  const bf16* sB = B + (size_t)(n0 + srow) * K + scol;
  char* const myl = lds + (w << 10);

  auto STG = [&](const bf16* s0, int buf, int isB, int h, int tt) {
    const bf16* g = s0 + ((size_t)(h << 7)) * K + ((size_t)tt << 6);
    char* lb = myl + (buf << 16) + (isB << 15) + (h << 14);
    gload16(g, lb);
    gload16(g + ((size_t)K << 6), lb + 8192);
  };

  const int rdswz = (li << 6) + ((lg << 4) ^ ((li & 8) << 2));

  f32x4 acc[8][4] = {};
  bf16x8 af[4][2], bfr[4][2];

  // prologue: tile0 full -> buf0; tile1 partial (B_lo,B_hi,A_lo) -> buf1
  STG(sB, 0, 1, 0, 0); STG(sB, 0, 1, 1, 0); STG(sA, 0, 0, 0, 0); STG(sA, 0, 0, 1, 0);
  asm volatile("s_waitcnt vmcnt(4)" ::: "memory");
  STG(sB, 1, 1, 0, 1); STG(sB, 1, 1, 1, 1); STG(sA, 1, 0, 0, 1);
  asm volatile("s_waitcnt vmcnt(6)" ::: "memory");
  __builtin_amdgcn_s_barrier();
  __builtin_amdgcn_sched_barrier(0);

  int t = 0;
  for (int tt = 0; tt + 3 < NT; tt += 2) {
    t = tt;     GTILE(0, 1, 1, 6);
    t = tt + 1; GTILE(1, 1, 1, 6);
  }
  t = NT - 2; GTILE(0, 1, 0, 0);
  t = NT - 1; GTILE(1, 0, 0, 0);

  // V-blocks of the QKV GEMM: write transposed into vt[bh][dd][p]
  if (EPI == 0 && n0 >= 2048) {
    #pragma unroll
    for (int mi = 0; mi < 8; mi++) {
      const int row = m0 + (wm << 7) + (mi << 4) + (lg << 2);
      const int p = row & 2047;
      const size_t bhb = (size_t)((row >> 11) << 4);
      #pragma unroll
      for (int ni = 0; ni < 4; ni++) {
        const int col = n0 + (wn << 6) + (ni << 4) + li;
        const int hh = (col >> 6) & 15, dd = col & 63;
        bf16x4 pk;
        pk[0] = (bf16)acc[mi][ni][0]; pk[1] = (bf16)acc[mi][ni][1];
        pk[2] = (bf16)acc[mi][ni][2]; pk[3] = (bf16)acc[mi][ni][3];
        *(bf16x4*)(vtb + ((bhb + hh) * 64 + dd) * 2048 + p) = pk;
      }
    }
    return;
  }

  #pragma unroll
  for (int mi = 0; mi < 8; mi++) {
    const int row = m0 + (wm << 7) + (mi << 4) + (lg << 2);
    #pragma unroll
    for (int ni = 0; ni < 4; ni++) {
      const int col = n0 + (wn << 6) + (ni << 4) + li;
      #pragma unroll
      for (int r2 = 0; r2 < 4; r2++) {
        const size_t idx = (size_t)(row + r2) * N + col;
        float v = acc[mi][ni][r2];
        if (EPI == 0) {
          outb[idx] = (bf16)v;
        } else if (EPI == 1) {
          float s = v + add[idx];
          outf[idx] = s; outb[idx] = (bf16)s;
        } else if (EPI == 2) {
          outb[idx] = (bf16)gelu_t(v + bias[col]);
        } else {
          outf[idx] = v + bias[col] + add[idx];
        }
      }
    }
  }
}

// ============ 256x128 8-phase GEMM (merged barriers), C = A @ B^T ===========
#define N_LDA2(BMI) { _Pragma("unroll") for (int i = 0; i < 2; i++) { \
    af[i][0] = *(const bf16x8*)(lds + abase + (((BMI)+i) << 11) + rdswz); \
    af[i][1] = *(const bf16x8*)(lds + abase + (((BMI)+i) << 11) + 1024 + rdswz); } }

#define N_LDB2(BNI) { _Pragma("unroll") for (int n = 0; n < 2; n++) { \
    bfr[(BNI)+n][0] = *(const bf16x8*)(lds + bbase + (((BNI)+n) << 11) + rdswz); \
    bfr[(BNI)+n][1] = *(const bf16x8*)(lds + bbase + (((BNI)+n) << 11) + 1024 + rdswz); } }

#define N_MMQ(MB, NB) { __builtin_amdgcn_s_setprio(1); \
    _Pragma("unroll") for (int i = 0; i < 2; i++) \
      _Pragma("unroll") for (int n = 0; n < 2; n++) { \
        acc[((MB)<<1)+i][((NB)<<1)+n] = MFMA(af[i][0], bfr[((NB)<<1)+n][0], acc[((MB)<<1)+i][((NB)<<1)+n]); \
        acc[((MB)<<1)+i][((NB)<<1)+n] = MFMA(af[i][1], bfr[((NB)<<1)+n][1], acc[((MB)<<1)+i][((NB)<<1)+n]); } \
    __builtin_amdgcn_s_setprio(0); }

#define NTILE(CUR, S1, S2, VM) { \
    const int abase = (CUR) * 49152 + ((wm >> 1) << 14) + ((wm & 1) << 13); \
    const int bbase = (CUR) * 49152 + 32768 + (wn << 13); \
    N_LDA2(0); N_LDB2(0); \
    if (S1) STA((CUR)^1, 1, t + 1); \
    __builtin_amdgcn_s_barrier(); LGKM0_FENCE(); \
    N_MMQ(0, 0); \
    N_LDB2(2); \
    if (S2) STB((CUR), 0, t + 2); \
    __builtin_amdgcn_s_barrier(); LGKM0_FENCE(); \
    N_MMQ(0, 1); \
    N_LDA2(2); \
    if (S2) STB((CUR), 1, t + 2); \
    __builtin_amdgcn_s_barrier(); LGKM0_FENCE(); \
    N_MMQ(1, 0); \
    if (S2) STA((CUR), 0, t + 2); \
    N_MMQ(1, 1); \
    asm volatile("s_waitcnt vmcnt(" #VM ")" ::: "memory"); \
    __builtin_amdgcn_s_barrier(); \
    __builtin_amdgcn_sched_barrier(0); }

template<int EPI>
__global__ __launch_bounds__(512, 2) void gemm128n(
    const bf16* __restrict__ A, const bf16* __restrict__ B,
    float* __restrict__ outf, bf16* __restrict__ outb,
    const float* __restrict__ add, const float* __restrict__ bias,
    int M, int N, int K, int gx)
{
  __shared__ __attribute__((aligned(128))) char lds[98304];
  const int tid = threadIdx.x;
  const int w = tid >> 6, l = tid & 63, lg = l >> 4, li = l & 15;
  const int wm = w >> 1, wn = w & 1;

  const int nwg = gridDim.x, orig = blockIdx.x;
  const int q = nwg >> 3, r = nwg & 7;
  const int xcd = orig & 7, pos = orig >> 3;
  const int wg = (xcd < r ? xcd*(q+1) : r*(q+1) + (xcd-r)*q) + pos;
  const int m0 = (wg / gx) << 8, n0 = (wg % gx) << 7;

  const int NT = K >> 6;

  const int srow = ((tid >> 7) << 4) + ((tid >> 2) & 15);
  const int scol = (((tid >> 6) & 1) << 5) + (((tid & 3) << 3) ^ (((tid >> 5) & 1) << 4));
  const bf16* sA = A + (size_t)(m0 + srow) * K + scol;
  const bf16* sB = B + (size_t)(n0 + srow) * K + scol;
  char* const myl = lds + (w << 10);

  auto STA = [&](int buf, int h, int tt) {
    const bf16* g = sA + ((size_t)(h << 7)) * K + ((size_t)tt << 6);
    char* lb = myl + buf * 49152 + (h << 14);
    gload16(g, lb);
    gload16(g + ((size_t)K << 6), lb + 8192);
  };
  auto STB = [&](int buf, int h, int tt) {
    const bf16* g = sB + ((size_t)(h << 6)) * K + ((size_t)tt << 6);
    gload16(g, myl + buf * 49152 + 32768 + (h << 13));
  };

  const int rdswz = (li << 6) + ((lg << 4) ^ ((li & 8) << 2));

  f32x4 acc[4][4] = {};
  bf16x8 af[2][2], bfr[4][2];

  STB(0, 0, 0); STB(0, 1, 0); STA(0, 0, 0); STA(0, 1, 0);
  STB(1, 0, 1); STB(1, 1, 1); STA(1, 0, 1);
  asm volatile("s_waitcnt vmcnt(4)" ::: "memory");
  __builtin_amdgcn_s_barrier();
  __builtin_amdgcn_sched_barrier(0);

  int t = 0;
  for (int tt = 0; tt + 3 < NT; tt += 2) {
    t = tt;     NTILE(0, 1, 1, 4);
    t = tt + 1; NTILE(1, 1, 1, 4);
  }
  t = NT - 2; NTILE(0, 1, 0, 0);
  t = NT - 1; NTILE(1, 0, 0, 0);

  #pragma unroll
  for (int mi = 0; mi < 4; mi++) {
    const int row = m0 + (wm << 6) + (mi << 4) + (lg << 2);
    #pragma unroll
    for (int ni = 0; ni < 4; ni++) {
      const int col = n0 + (wn << 6) + (ni << 4) + li;
      #pragma unroll
      for (int r2 = 0; r2 < 4; r2++) {
        const size_t idx = (size_t)(row + r2) * N + col;
        float v = acc[mi][ni][r2];
        if (EPI == 0) {
          outb[idx] = (bf16)v;
        } else if (EPI == 1) {
          float s = v + add[idx];
          outf[idx] = s; outb[idx] = (bf16)s;
        } else if (EPI == 2) {
          outb[idx] = (bf16)gelu_t(v + bias[col]);
        } else {
          outf[idx] = v + bias[col] + add[idx];
        }
      }
    }
  }
}

// ---------------- causal flash attention (v3, unchanged) --------------------
__global__ __launch_bounds__(256) void attn_kernel(const bf16* __restrict__ qkv,
                                                   const bf16* __restrict__ vt,
                                                   bf16* __restrict__ z)
{
  __shared__ bf16 Ksh[2][64*64];
  __shared__ bf16 Vsh[2][64*64];
  __shared__ bf16 Pl[4*16*64];

  const int tid = threadIdx.x;
  const int w = tid >> 6, l = tid & 63, lg = l >> 4, li = l & 15;
  const int pr = blockIdx.x & 15, bh = blockIdx.x >> 4;
  const int h = bh & 15, b = bh >> 4;
  const size_t tb = (size_t)b * 2048;

  const int srow = tid >> 3, sc = tid & 7;
  const bf16* Kg = qkv + (tb + srow) * 3072 + 1024 + (h << 6) + ((sc ^ (srow & 7)) << 3);
  const bf16* Vg = vt + ((size_t)bh * 64 + srow) * 2048 + ((sc ^ (srow & 7)) << 3);

  char* pw = (char*)Pl + (w << 11) + li * 128;
  const int psw = (li & 3) << 5;

  for (int hf = 0; hf < 2; ++hf) {
    const int qt = hf ? pr : (31 - pr);
    const int qw = (qt << 6) + (w << 4);

    const bf16* Qp = qkv + (tb + qw + li) * 3072 + (h << 6);
    bf16x8 qa0 = *(const bf16x8*)(Qp + (lg << 3));
    bf16x8 qa1 = *(const bf16x8*)(Qp + 32 + (lg << 3));
    #pragma unroll
    for (int e = 0; e < 8; e++) {
      qa0[e] = (bf16)((float)qa0[e] * 0.1803368801f);
      qa1[e] = (bf16)((float)qa1[e] * 0.1803368801f);
    }

    f32x4 zacc[4] = {};
    float mR = -1e30f, lS = 0.f;
    const int nkt = qt + 1;

    gload16(Kg,                   (bf16*)Ksh[0] + (w << 9));
    gload16(Kg + (size_t)32*3072, (bf16*)Ksh[0] + 2048 + (w << 9));
    gload16(Vg,                   (bf16*)Vsh[0] + (w << 9));
    gload16(Vg + (size_t)32*2048, (bf16*)Vsh[0] + 2048 + (w << 9));
    __syncthreads();

    for (int kt = 0; kt < nkt; ++kt) {
      const int cur = kt & 1;
      const int pb = kt << 6;

      if (kt + 1 < nkt) {
        const int nb = cur ^ 1;
        const size_t ko = (size_t)(pb + 64) * 3072;
        gload16(Kg + ko,                   (bf16*)Ksh[nb] + (w << 9));
        gload16(Kg + ko + (size_t)32*3072, (bf16*)Ksh[nb] + 2048 + (w << 9));
        gload16(Vg + pb + 64,                   (bf16*)Vsh[nb] + (w << 9));
        gload16(Vg + pb + 64 + (size_t)32*2048, (bf16*)Vsh[nb] + 2048 + (w << 9));
      }

      f32x4 s[4];
      __builtin_amdgcn_s_setprio(1);
      #pragma unroll
      for (int sub = 0; sub < 4; ++sub) {
        const char* kr = (const char*)Ksh[cur] + ((sub << 4) + li) * 128;
        const int c0 = (lg ^ (li & 7)) << 4;
        bf16x8 kb0 = *(const bf16x8*)(kr + c0);
        bf16x8 kb1 = *(const bf16x8*)(kr + (c0 ^ 64));
        f32x4 a2 = {};
        a2 = MFMA(kb0, qa0, a2);
        a2 = MFMA(kb1, qa1, a2);
        s[sub] = a2;
      }
      __builtin_amdgcn_s_setprio(0);

      if (pb + 63 > qw) {
        #pragma unroll
        for (int sub = 0; sub < 4; ++sub)
          #pragma unroll
          for (int r = 0; r < 4; ++r)
            if (pb + (sub << 4) + (lg << 2) + r > qw + li) s[sub][r] = -1e30f;
      }

      f32x4 m4;
      #pragma unroll
      for (int r = 0; r < 4; ++r)
        m4[r] = fmaxf(fmaxf(s[0][r], s[1][r]), fmaxf(s[2][r], s[3][r]));
      float mx = fmaxf(fmaxf(m4[0], m4[1]), fmaxf(m4[2], m4[3]));
      mx = fmaxf(mx, __shfl_xor(mx, 16));
      mx = fmaxf(mx, __shfl_xor(mx, 32));

      float mn = mR;
      if (!__all(mx <= mR + 11.5f)) {
        mn = fmaxf(mR, mx);
        float c = EXP2F(mR - mn);
        mR = mn;
        lS *= c;
        float cr0 = __shfl(c, (lg << 2) + 0);
        float cr1 = __shfl(c, (lg << 2) + 1);
        float cr2 = __shfl(c, (lg << 2) + 2);
        float cr3 = __shfl(c, (lg << 2) + 3);
        #pragma unroll
        for (int d = 0; d < 4; ++d) {
          zacc[d][0] *= cr0; zacc[d][1] *= cr1;
          zacc[d][2] *= cr2; zacc[d][3] *= cr3;
        }
      }

      f32x4 p[4];
      #pragma unroll
      for (int sub = 0; sub < 4; ++sub)
        #pragma unroll
        for (int r = 0; r < 4; ++r)
          p[sub][r] = EXP2F(s[sub][r] - mn);
      f32x4 t4 = p[0] + p[1] + p[2] + p[3];
      lS += (t4[0] + t4[1]) + (t4[2] + t4[3]);

      #pragma unroll
      for (int sub = 0; sub < 4; ++sub) {
        bf16x4 pk;
        pk[0] = (bf16)p[sub][0]; pk[1] = (bf16)p[sub][1];
        pk[2] = (bf16)p[sub][2]; pk[3] = (bf16)p[sub][3];
        *(bf16x4*)(pw + (((sub << 5) + (lg << 3)) ^ psw)) = pk;
      }

      __builtin_amdgcn_s_setprio(1);
      #pragma unroll
      for (int kc = 0; kc < 2; ++kc) {
        bf16x8 pa = *(const bf16x8*)(pw + (((kc << 6) + (lg << 4)) ^ psw));
        #pragma unroll
        for (int d = 0; d < 4; ++d) {
          const char* vr = (const char*)Vsh[cur] + ((d << 4) + li) * 128;
          bf16x8 vb = *(const bf16x8*)(vr + ((((kc << 2) + lg) ^ (li & 7)) << 4));
          zacc[d] = MFMA(pa, vb, zacc[d]);
        }
      }
      __builtin_amdgcn_s_setprio(0);

      __syncthreads();
    }

    lS += __shfl_xor(lS, 16);
    lS += __shfl_xor(lS, 32);

    float rls[4];
    #pragma unroll
    for (int r = 0; r < 4; ++r) rls[r] = 1.0f / __shfl(lS, (lg << 2) + r);
    bf16* zp = z + (tb + qw) * 1024 + (h << 6);
    #pragma unroll
    for (int d = 0; d < 4; ++d)
      #pragma unroll
      for (int r = 0; r < 4; ++r)
        zp[(size_t)((lg << 2) + r) * 1024 + (d << 4) + li] = (bf16)(zacc[d][r] * rls[r]);
  }
}

// ---------------- launch ----------------------------------------------------
extern "C" void kernel_launch(void* const* d_in, const int* in_sizes, int n_in,
                              void* d_out, int out_size, void* d_ws, size_t ws_size,
                              hipStream_t stream)
{
  const float* x     = (const float*)d_in[0];
  const float* W_K   = (const float*)d_in[1];
  const float* W_Q   = (const float*)d_in[2];
  const float* W_V   = (const float*)d_in[3];
  const float* W_O   = (const float*)d_in[4];
  const float* W_in  = (const float*)d_in[5];
  const float* b_in  = (const float*)d_in[6];
  const float* W_out = (const float*)d_in[7];
  const float* b_out = (const float*)d_in[8];
  float* out = (float*)d_out;

  char* ws = (char*)d_ws;
  bf16*  xb   = (bf16*)ws;  ws += (size_t)8192*1024*2;
  bf16*  wqkv = (bf16*)ws;  ws += (size_t)3072*1024*2;
  bf16*  wo   = (bf16*)ws;  ws += (size_t)1024*1024*2;
  bf16*  win  = (bf16*)ws;  ws += (size_t)4096*1024*2;
  bf16*  wout = (bf16*)ws;  ws += (size_t)1024*4096*2;
  bf16*  qkv  = (bf16*)ws;  ws += (size_t)8192*3072*2;
  bf16*  zb   = (bf16*)ws;  ws += (size_t)8192*1024*2;
  float* x1f  = (float*)ws; ws += (size_t)8192*1024*4;
  bf16*  x1b  = (bf16*)ws;  ws += (size_t)8192*1024*2;
  bf16*  hb   = (bf16*)ws;  // 8192*4096*2
  bf16*  vtb  = hb;         // alias: vt[64][64][2048] used before MLP1 writes hb

  auto cast = [&](const float* src, bf16* dst, size_t n) {
    int n8 = (int)(n / 8);
    cast_kernel<<<dim3((n8 + 255) / 256), dim3(256), 0, stream>>>(src, dst, n8);
  };
  cast(x,     xb,               (size_t)8192*1024);
  cast(W_Q,   wqkv,             (size_t)1024*1024);
  cast(W_K,   wqkv + 1024*1024, (size_t)1024*1024);
  cast(W_V,   wqkv + 2048*1024, (size_t)1024*1024);
  cast(W_O,   wo,               (size_t)1024*1024);
  cast(W_in,  win,              (size_t)4096*1024);
  cast(W_out, wout,             (size_t)1024*4096);

  // QKV = x @ Wqkv^T  [8192 x 3072]; V-blocks land transposed in vtb
  gemm256<0><<<dim3(384), 512, 0, stream>>>(xb, wqkv, nullptr, qkv, nullptr, nullptr, vtb, 8192, 3072, 1024, 12);
  // causal attention -> z [8192 x 1024]
  attn_kernel<<<dim3(1024), 256, 0, stream>>>(qkv, vtb, zb);
  // x1 = x + z @ W_O^T   (256x128, 256 blocks)
  gemm128n<1><<<dim3(256), 512, 0, stream>>>(zb, wo, x1f, x1b, x, nullptr, 8192, 1024, 1024, 8);
  // h = gelu(x1 @ W_in^T + b_in)  (256^2, 512 blocks)
  gemm256<2><<<dim3(512), 512, 0, stream>>>(x1b, win, nullptr, hb, nullptr, b_in, nullptr, 8192, 4096, 1024, 16);
  // out = x1 + h @ W_out^T + b_out  (256x128, K=4096, 256 blocks)
  gemm128n<3><<<dim3(256), 512, 0, stream>>>(hb, wout, out, nullptr, x1f, b_out, 8192, 1024, 4096, 8);
}

// Round 8
// 310.415 us; speedup vs baseline: 2.1824x; 1.0790x over previous
//
#include <hip/hip_runtime.h>
#include <hip/hip_bf16.h>

typedef __bf16 bf16;
typedef __bf16 bf16x8 __attribute__((ext_vector_type(8)));
typedef __bf16 bf16x4 __attribute__((ext_vector_type(4)));
typedef float  f32x4  __attribute__((ext_vector_type(4)));

#define MFMA(a,b,c) __builtin_amdgcn_mfma_f32_16x16x32_bf16(a,b,c,0,0,0)
#define EXP2F(x) __builtin_amdgcn_exp2f(x)

__device__ __forceinline__ void gload16(const void* g, void* l) {
  __builtin_amdgcn_global_load_lds((__attribute__((address_space(1))) void*)(g),
                                   (__attribute__((address_space(3))) void*)(l), 16, 0, 0);
}

// ---------------- fused fp32 -> bf16 cast (7 segments, one launch) ----------
struct CastSegs {
  const float* src[7];
  bf16* dst[7];
  int cum[8];   // cumulative n8 boundaries
};

__global__ void cast_multi(CastSegs s) {
  int i = blockIdx.x * 256 + threadIdx.x;
  if (i >= s.cum[7]) return;
  int k = 0;
  #pragma unroll
  for (int j = 1; j < 7; ++j) if (i >= s.cum[j]) k = j;
  int off = i - s.cum[k];
  const float4* p = (const float4*)s.src[k];
  float4 a = p[2*off], b = p[2*off+1];
  bf16x8 v;
  v[0]=(bf16)a.x; v[1]=(bf16)a.y; v[2]=(bf16)a.z; v[3]=(bf16)a.w;
  v[4]=(bf16)b.x; v[5]=(bf16)b.y; v[6]=(bf16)b.z; v[7]=(bf16)b.w;
  *(bf16x8*)(s.dst[k] + (size_t)8*off) = v;
}

__device__ __forceinline__ float gelu_t(float s) {
  float u = s * (0.7978845608f + 0.0356774081f * s * s);
  return s / (1.0f + EXP2F(-2.885390082f * u));
}

#define LGKM0_FENCE() { asm volatile("s_waitcnt lgkmcnt(0)" ::: "memory"); \
                        __builtin_amdgcn_sched_barrier(0); }

// ============ 256x256 8-phase GEMM (merged barriers), C = A @ B^T ===========
#define LDA_PH(MI2) { _Pragma("unroll") for (int i = 0; i < 4; i++) { \
    af[i][0] = *(const bf16x8*)(lds + ab + ((((MI2)<<2)+i) << 11) + rdswz); \
    af[i][1] = *(const bf16x8*)(lds + ab + ((((MI2)<<2)+i) << 11) + 1024 + rdswz); } }

#define LDB_PH(NI2) { _Pragma("unroll") for (int n = 0; n < 2; n++) { \
    bfr[((NI2)<<1)+n][0] = *(const bf16x8*)(lds + bb + (((((NI2)<<1)+n)) << 11) + rdswz); \
    bfr[((NI2)<<1)+n][1] = *(const bf16x8*)(lds + bb + (((((NI2)<<1)+n)) << 11) + 1024 + rdswz); } }

#define MM_PH(MI2, NI2) { __builtin_amdgcn_s_setprio(1); \
    _Pragma("unroll") for (int i = 0; i < 4; i++) \
      _Pragma("unroll") for (int n = 0; n < 2; n++) { \
        acc[((MI2)<<2)+i][((NI2)<<1)+n] = MFMA(af[i][0], bfr[((NI2)<<1)+n][0], acc[((MI2)<<2)+i][((NI2)<<1)+n]); \
        acc[((MI2)<<2)+i][((NI2)<<1)+n] = MFMA(af[i][1], bfr[((NI2)<<1)+n][1], acc[((MI2)<<2)+i][((NI2)<<1)+n]); } \
    __builtin_amdgcn_s_setprio(0); }

#define GTILE(CUR, S1, S2, VM) { \
    const int ab = ((CUR) << 16) + (wm << 14); \
    const int bb = ((CUR) << 16) + 32768 + (wn << 13); \
    LDA_PH(0); LDB_PH(0); \
    if (S1) STG(sA, (CUR)^1, 0, 1, t + 1); \
    asm volatile("s_waitcnt lgkmcnt(8)" ::: "memory"); \
    __builtin_amdgcn_s_barrier(); LGKM0_FENCE(); \
    MM_PH(0, 0); \
    LDB_PH(1); \
    if (S2) STG(sB, (CUR), 1, 0, t + 2); \
    __builtin_amdgcn_s_barrier(); LGKM0_FENCE(); \
    MM_PH(0, 1); \
    LDA_PH(1); \
    if (S2) STG(sB, (CUR), 1, 1, t + 2); \
    __builtin_amdgcn_s_barrier(); LGKM0_FENCE(); \
    MM_PH(1, 0); \
    if (S2) STG(sA, (CUR), 0, 0, t + 2); \
    MM_PH(1, 1); \
    asm volatile("s_waitcnt vmcnt(" #VM ")" ::: "memory"); \
    __builtin_amdgcn_s_barrier(); \
    __builtin_amdgcn_sched_barrier(0); }

template<int EPI>
__global__ __launch_bounds__(512, 2) void gemm256(
    const bf16* __restrict__ A, const bf16* __restrict__ B,
    float* __restrict__ outf, bf16* __restrict__ outb,
    const float* __restrict__ add, const float* __restrict__ bias,
    int M, int N, int K, int gx)
{
  __shared__ __attribute__((aligned(128))) char lds[131072];
  const int tid = threadIdx.x;
  const int w = tid >> 6, l = tid & 63, lg = l >> 4, li = l & 15;
  const int wm = w >> 2, wn = w & 3;

  const int nwg = gridDim.x, orig = blockIdx.x;
  const int q = nwg >> 3, r = nwg & 7;
  const int xcd = orig & 7, pos = orig >> 3;
  const int wg = (xcd < r ? xcd*(q+1) : r*(q+1) + (xcd-r)*q) + pos;
  const int m0 = (wg / gx) << 8, n0 = (wg % gx) << 8;

  const int NT = K >> 6;   // NT even

  const int srow = ((tid >> 7) << 4) + ((tid >> 2) & 15);
  const int scol = (((tid >> 6) & 1) << 5) + (((tid & 3) << 3) ^ (((tid >> 5) & 1) << 4));
  const bf16* sA = A + (size_t)(m0 + srow) * K + scol;
  const bf16* sB = B + (size_t)(n0 + srow) * K + scol;
  char* const myl = lds + (w << 10);

  auto STG = [&](const bf16* s0, int buf, int isB, int h, int tt) {
    const bf16* g = s0 + ((size_t)(h << 7)) * K + ((size_t)tt << 6);
    char* lb = myl + (buf << 16) + (isB << 15) + (h << 14);
    gload16(g, lb);
    gload16(g + ((size_t)K << 6), lb + 8192);
  };

  const int rdswz = (li << 6) + ((lg << 4) ^ ((li & 8) << 2));

  f32x4 acc[8][4] = {};
  bf16x8 af[4][2], bfr[4][2];

  STG(sB, 0, 1, 0, 0); STG(sB, 0, 1, 1, 0); STG(sA, 0, 0, 0, 0); STG(sA, 0, 0, 1, 0);
  asm volatile("s_waitcnt vmcnt(4)" ::: "memory");
  STG(sB, 1, 1, 0, 1); STG(sB, 1, 1, 1, 1); STG(sA, 1, 0, 0, 1);
  asm volatile("s_waitcnt vmcnt(6)" ::: "memory");
  __builtin_amdgcn_s_barrier();
  __builtin_amdgcn_sched_barrier(0);

  int t = 0;
  for (int tt = 0; tt + 3 < NT; tt += 2) {
    t = tt;     GTILE(0, 1, 1, 6);
    t = tt + 1; GTILE(1, 1, 1, 6);
  }
  t = NT - 2; GTILE(0, 1, 0, 0);
  t = NT - 1; GTILE(1, 0, 0, 0);

  #pragma unroll
  for (int mi = 0; mi < 8; mi++) {
    const int row = m0 + (wm << 7) + (mi << 4) + (lg << 2);
    #pragma unroll
    for (int ni = 0; ni < 4; ni++) {
      const int col = n0 + (wn << 6) + (ni << 4) + li;
      #pragma unroll
      for (int r2 = 0; r2 < 4; r2++) {
        const size_t idx = (size_t)(row + r2) * N + col;
        float v = acc[mi][ni][r2];
        if (EPI == 0) {
          outb[idx] = (bf16)v;
        } else if (EPI == 1) {
          float s = v + add[idx];
          outf[idx] = s; outb[idx] = (bf16)s;
        } else if (EPI == 2) {
          outb[idx] = (bf16)gelu_t(v + bias[col]);
        } else {
          outf[idx] = v + bias[col] + add[idx];
        }
      }
    }
  }
}

// ============ 256x128 8-phase GEMM (merged barriers), C = A @ B^T ===========
// EPI 0: QKV epilogue — K/Q blocks write outb, V blocks (n0>=2048) write
// transposed into vt[bh][dd][p].
#define N_LDA2(BMI) { _Pragma("unroll") for (int i = 0; i < 2; i++) { \
    af[i][0] = *(const bf16x8*)(lds + abase + (((BMI)+i) << 11) + rdswz); \
    af[i][1] = *(const bf16x8*)(lds + abase + (((BMI)+i) << 11) + 1024 + rdswz); } }

#define N_LDB2(BNI) { _Pragma("unroll") for (int n = 0; n < 2; n++) { \
    bfr[(BNI)+n][0] = *(const bf16x8*)(lds + bbase + (((BNI)+n) << 11) + rdswz); \
    bfr[(BNI)+n][1] = *(const bf16x8*)(lds + bbase + (((BNI)+n) << 11) + 1024 + rdswz); } }

#define N_MMQ(MB, NB) { __builtin_amdgcn_s_setprio(1); \
    _Pragma("unroll") for (int i = 0; i < 2; i++) \
      _Pragma("unroll") for (int n = 0; n < 2; n++) { \
        acc[((MB)<<1)+i][((NB)<<1)+n] = MFMA(af[i][0], bfr[((NB)<<1)+n][0], acc[((MB)<<1)+i][((NB)<<1)+n]); \
        acc[((MB)<<1)+i][((NB)<<1)+n] = MFMA(af[i][1], bfr[((NB)<<1)+n][1], acc[((MB)<<1)+i][((NB)<<1)+n]); } \
    __builtin_amdgcn_s_setprio(0); }

#define NTILE(CUR, S1, S2, VM) { \
    const int abase = (CUR) * 49152 + ((wm >> 1) << 14) + ((wm & 1) << 13); \
    const int bbase = (CUR) * 49152 + 32768 + (wn << 13); \
    N_LDA2(0); N_LDB2(0); \
    if (S1) STA((CUR)^1, 1, t + 1); \
    __builtin_amdgcn_s_barrier(); LGKM0_FENCE(); \
    N_MMQ(0, 0); \
    N_LDB2(2); \
    if (S2) STB((CUR), 0, t + 2); \
    __builtin_amdgcn_s_barrier(); LGKM0_FENCE(); \
    N_MMQ(0, 1); \
    N_LDA2(2); \
    if (S2) STB((CUR), 1, t + 2); \
    __builtin_amdgcn_s_barrier(); LGKM0_FENCE(); \
    N_MMQ(1, 0); \
    if (S2) STA((CUR), 0, t + 2); \
    N_MMQ(1, 1); \
    asm volatile("s_waitcnt vmcnt(" #VM ")" ::: "memory"); \
    __builtin_amdgcn_s_barrier(); \
    __builtin_amdgcn_sched_barrier(0); }

template<int EPI>
__global__ __launch_bounds__(512, 2) void gemm128n(
    const bf16* __restrict__ A, const bf16* __restrict__ B,
    float* __restrict__ outf, bf16* __restrict__ outb,
    const float* __restrict__ add, const float* __restrict__ bias,
    bf16* __restrict__ vtb,
    int M, int N, int K, int gx)
{
  __shared__ __attribute__((aligned(128))) char lds[98304];
  const int tid = threadIdx.x;
  const int w = tid >> 6, l = tid & 63, lg = l >> 4, li = l & 15;
  const int wm = w >> 1, wn = w & 1;

  const int nwg = gridDim.x, orig = blockIdx.x;
  const int q = nwg >> 3, r = nwg & 7;
  const int xcd = orig & 7, pos = orig >> 3;
  const int wg = (xcd < r ? xcd*(q+1) : r*(q+1) + (xcd-r)*q) + pos;
  const int m0 = (wg / gx) << 8, n0 = (wg % gx) << 7;

  const int NT = K >> 6;

  const int srow = ((tid >> 7) << 4) + ((tid >> 2) & 15);
  const int scol = (((tid >> 6) & 1) << 5) + (((tid & 3) << 3) ^ (((tid >> 5) & 1) << 4));
  const bf16* sA = A + (size_t)(m0 + srow) * K + scol;
  const bf16* sB = B + (size_t)(n0 + srow) * K + scol;
  char* const myl = lds + (w << 10);

  auto STA = [&](int buf, int h, int tt) {
    const bf16* g = sA + ((size_t)(h << 7)) * K + ((size_t)tt << 6);
    char* lb = myl + buf * 49152 + (h << 14);
    gload16(g, lb);
    gload16(g + ((size_t)K << 6), lb + 8192);
  };
  auto STB = [&](int buf, int h, int tt) {
    const bf16* g = sB + ((size_t)(h << 6)) * K + ((size_t)tt << 6);
    gload16(g, myl + buf * 49152 + 32768 + (h << 13));
  };

  const int rdswz = (li << 6) + ((lg << 4) ^ ((li & 8) << 2));

  f32x4 acc[4][4] = {};
  bf16x8 af[2][2], bfr[4][2];

  STB(0, 0, 0); STB(0, 1, 0); STA(0, 0, 0); STA(0, 1, 0);
  STB(1, 0, 1); STB(1, 1, 1); STA(1, 0, 1);
  asm volatile("s_waitcnt vmcnt(4)" ::: "memory");
  __builtin_amdgcn_s_barrier();
  __builtin_amdgcn_sched_barrier(0);

  int t = 0;
  for (int tt = 0; tt + 3 < NT; tt += 2) {
    t = tt;     NTILE(0, 1, 1, 4);
    t = tt + 1; NTILE(1, 1, 1, 4);
  }
  t = NT - 2; NTILE(0, 1, 0, 0);
  t = NT - 1; NTILE(1, 0, 0, 0);

  // QKV V-blocks: write transposed into vt[bh][dd][p]
  if (EPI == 0 && n0 >= 2048) {
    #pragma unroll
    for (int mi = 0; mi < 4; mi++) {
      const int row = m0 + (wm << 6) + (mi << 4) + (lg << 2);
      const int p = row & 2047;
      const size_t bhb = (size_t)((row >> 11) << 4);
      #pragma unroll
      for (int ni = 0; ni < 4; ni++) {
        const int col = n0 + (wn << 6) + (ni << 4) + li;
        const int hh = (col >> 6) & 15, dd = col & 63;
        bf16x4 pk;
        pk[0] = (bf16)acc[mi][ni][0]; pk[1] = (bf16)acc[mi][ni][1];
        pk[2] = (bf16)acc[mi][ni][2]; pk[3] = (bf16)acc[mi][ni][3];
        *(bf16x4*)(vtb + ((bhb + hh) * 64 + dd) * 2048 + p) = pk;
      }
    }
    return;
  }

  #pragma unroll
  for (int mi = 0; mi < 4; mi++) {
    const int row = m0 + (wm << 6) + (mi << 4) + (lg << 2);
    #pragma unroll
    for (int ni = 0; ni < 4; ni++) {
      const int col = n0 + (wn << 6) + (ni << 4) + li;
      #pragma unroll
      for (int r2 = 0; r2 < 4; r2++) {
        const size_t idx = (size_t)(row + r2) * N + col;
        float v = acc[mi][ni][r2];
        if (EPI == 0) {
          outb[idx] = (bf16)v;
        } else if (EPI == 1) {
          float s = v + add[idx];
          outf[idx] = s; outb[idx] = (bf16)s;
        } else if (EPI == 2) {
          outb[idx] = (bf16)gelu_t(v + bias[col]);
        } else {
          outf[idx] = v + bias[col] + add[idx];
        }
      }
    }
  }
}

// ---------------- causal flash attention (v3 + bh-XCD grouping) --------------
// XCD x owns bh in {8x..8x+7}: per-XCD K/V working set = 4MB = one XCD L2.
__global__ __launch_bounds__(256) void attn_kernel(const bf16* __restrict__ qkv,
                                                   const bf16* __restrict__ vt,
                                                   bf16* __restrict__ z)
{
  __shared__ bf16 Ksh[2][64*64];
  __shared__ bf16 Vsh[2][64*64];
  __shared__ bf16 Pl[4*16*64];

  const int tid = threadIdx.x;
  const int w = tid >> 6, l = tid & 63, lg = l >> 4, li = l & 15;
  const int orig = blockIdx.x;
  const int xcd = orig & 7, sub = orig >> 3;
  const int bh = (xcd << 3) + (sub >> 4);
  const int pr = sub & 15;
  const int h = bh & 15, b = bh >> 4;
  const size_t tb = (size_t)b * 2048;

  const int srow = tid >> 3, sc = tid & 7;
  const bf16* Kg = qkv + (tb + srow) * 3072 + 1024 + (h << 6) + ((sc ^ (srow & 7)) << 3);
  const bf16* Vg = vt + ((size_t)bh * 64 + srow) * 2048 + ((sc ^ (srow & 7)) << 3);

  char* pw = (char*)Pl + (w << 11) + li * 128;
  const int psw = (li & 3) << 5;

  for (int hf = 0; hf < 2; ++hf) {
    const int qt = hf ? pr : (31 - pr);
    const int qw = (qt << 6) + (w << 4);

    const bf16* Qp = qkv + (tb + qw + li) * 3072 + (h << 6);
    bf16x8 qa0 = *(const bf16x8*)(Qp + (lg << 3));
    bf16x8 qa1 = *(const bf16x8*)(Qp + 32 + (lg << 3));
    #pragma unroll
    for (int e = 0; e < 8; e++) {
      qa0[e] = (bf16)((float)qa0[e] * 0.1803368801f);
      qa1[e] = (bf16)((float)qa1[e] * 0.1803368801f);
    }

    f32x4 zacc[4] = {};
    float mR = -1e30f, lS = 0.f;
    const int nkt = qt + 1;

    gload16(Kg,                   (bf16*)Ksh[0] + (w << 9));
    gload16(Kg + (size_t)32*3072, (bf16*)Ksh[0] + 2048 + (w << 9));
    gload16(Vg,                   (bf16*)Vsh[0] + (w << 9));
    gload16(Vg + (size_t)32*2048, (bf16*)Vsh[0] + 2048 + (w << 9));
    __syncthreads();

    for (int kt = 0; kt < nkt; ++kt) {
      const int cur = kt & 1;
      const int pb = kt << 6;

      if (kt + 1 < nkt) {
        const int nb = cur ^ 1;
        const size_t ko = (size_t)(pb + 64) * 3072;
        gload16(Kg + ko,                   (bf16*)Ksh[nb] + (w << 9));
        gload16(Kg + ko + (size_t)32*3072, (bf16*)Ksh[nb] + 2048 + (w << 9));
        gload16(Vg + pb + 64,                   (bf16*)Vsh[nb] + (w << 9));
        gload16(Vg + pb + 64 + (size_t)32*2048, (bf16*)Vsh[nb] + 2048 + (w << 9));
      }

      f32x4 s[4];
      __builtin_amdgcn_s_setprio(1);
      #pragma unroll
      for (int sub2 = 0; sub2 < 4; ++sub2) {
        const char* kr = (const char*)Ksh[cur] + ((sub2 << 4) + li) * 128;
        const int c0 = (lg ^ (li & 7)) << 4;
        bf16x8 kb0 = *(const bf16x8*)(kr + c0);
        bf16x8 kb1 = *(const bf16x8*)(kr + (c0 ^ 64));
        f32x4 a2 = {};
        a2 = MFMA(kb0, qa0, a2);
        a2 = MFMA(kb1, qa1, a2);
        s[sub2] = a2;
      }
      __builtin_amdgcn_s_setprio(0);

      if (pb + 63 > qw) {
        #pragma unroll
        for (int sub2 = 0; sub2 < 4; ++sub2)
          #pragma unroll
          for (int r = 0; r < 4; ++r)
            if (pb + (sub2 << 4) + (lg << 2) + r > qw + li) s[sub2][r] = -1e30f;
      }

      f32x4 m4;
      #pragma unroll
      for (int r = 0; r < 4; ++r)
        m4[r] = fmaxf(fmaxf(s[0][r], s[1][r]), fmaxf(s[2][r], s[3][r]));
      float mx = fmaxf(fmaxf(m4[0], m4[1]), fmaxf(m4[2], m4[3]));
      mx = fmaxf(mx, __shfl_xor(mx, 16));
      mx = fmaxf(mx, __shfl_xor(mx, 32));

      float mn = mR;
      if (!__all(mx <= mR + 11.5f)) {
        mn = fmaxf(mR, mx);
        float c = EXP2F(mR - mn);
        mR = mn;
        lS *= c;
        float cr0 = __shfl(c, (lg << 2) + 0);
        float cr1 = __shfl(c, (lg << 2) + 1);
        float cr2 = __shfl(c, (lg << 2) + 2);
        float cr3 = __shfl(c, (lg << 2) + 3);
        #pragma unroll
        for (int d = 0; d < 4; ++d) {
          zacc[d][0] *= cr0; zacc[d][1] *= cr1;
          zacc[d][2] *= cr2; zacc[d][3] *= cr3;
        }
      }

      f32x4 p[4];
      #pragma unroll
      for (int sub2 = 0; sub2 < 4; ++sub2)
        #pragma unroll
        for (int r = 0; r < 4; ++r)
          p[sub2][r] = EXP2F(s[sub2][r] - mn);
      f32x4 t4 = p[0] + p[1] + p[2] + p[3];
      lS += (t4[0] + t4[1]) + (t4[2] + t4[3]);

      #pragma unroll
      for (int sub2 = 0; sub2 < 4; ++sub2) {
        bf16x4 pk;
        pk[0] = (bf16)p[sub2][0]; pk[1] = (bf16)p[sub2][1];
        pk[2] = (bf16)p[sub2][2]; pk[3] = (bf16)p[sub2][3];
        *(bf16x4*)(pw + (((sub2 << 5) + (lg << 3)) ^ psw)) = pk;
      }

      __builtin_amdgcn_s_setprio(1);
      #pragma unroll
      for (int kc = 0; kc < 2; ++kc) {
        bf16x8 pa = *(const bf16x8*)(pw + (((kc << 6) + (lg << 4)) ^ psw));
        #pragma unroll
        for (int d = 0; d < 4; ++d) {
          const char* vr = (const char*)Vsh[cur] + ((d << 4) + li) * 128;
          bf16x8 vb = *(const bf16x8*)(vr + ((((kc << 2) + lg) ^ (li & 7)) << 4));
          zacc[d] = MFMA(pa, vb, zacc[d]);
        }
      }
      __builtin_amdgcn_s_setprio(0);

      __syncthreads();
    }

    lS += __shfl_xor(lS, 16);
    lS += __shfl_xor(lS, 32);

    float rls[4];
    #pragma unroll
    for (int r = 0; r < 4; ++r) rls[r] = 1.0f / __shfl(lS, (lg << 2) + r);
    bf16* zp = z + (tb + qw) * 1024 + (h << 6);
    #pragma unroll
    for (int d = 0; d < 4; ++d)
      #pragma unroll
      for (int r = 0; r < 4; ++r)
        zp[(size_t)((lg << 2) + r) * 1024 + (d << 4) + li] = (bf16)(zacc[d][r] * rls[r]);
  }
}

// ---------------- launch ----------------------------------------------------
extern "C" void kernel_launch(void* const* d_in, const int* in_sizes, int n_in,
                              void* d_out, int out_size, void* d_ws, size_t ws_size,
                              hipStream_t stream)
{
  const float* x     = (const float*)d_in[0];
  const float* W_K   = (const float*)d_in[1];
  const float* W_Q   = (const float*)d_in[2];
  const float* W_V   = (const float*)d_in[3];
  const float* W_O   = (const float*)d_in[4];
  const float* W_in  = (const float*)d_in[5];
  const float* b_in  = (const float*)d_in[6];
  const float* W_out = (const float*)d_in[7];
  const float* b_out = (const float*)d_in[8];
  float* out = (float*)d_out;

  char* ws = (char*)d_ws;
  bf16*  xb   = (bf16*)ws;  ws += (size_t)8192*1024*2;
  bf16*  wqkv = (bf16*)ws;  ws += (size_t)3072*1024*2;
  bf16*  wo   = (bf16*)ws;  ws += (size_t)1024*1024*2;
  bf16*  win  = (bf16*)ws;  ws += (size_t)4096*1024*2;
  bf16*  wout = (bf16*)ws;  ws += (size_t)1024*4096*2;
  bf16*  qkv  = (bf16*)ws;  ws += (size_t)8192*3072*2;
  bf16*  zb   = (bf16*)ws;  ws += (size_t)8192*1024*2;
  float* x1f  = (float*)ws; ws += (size_t)8192*1024*4;
  bf16*  x1b  = (bf16*)ws;  ws += (size_t)8192*1024*2;
  bf16*  hb   = (bf16*)ws;  // 8192*4096*2
  bf16*  vtb  = hb;         // alias: vt[64][64][2048] used before MLP1 writes hb

  // fused casts (one launch): x + 6 weight tensors
  CastSegs cs;
  const float* srcs[7] = { x, W_Q, W_K, W_V, W_O, W_in, W_out };
  bf16* dsts[7] = { xb, wqkv, wqkv + 1024*1024, wqkv + 2048*1024, wo, win, wout };
  int n8s[7] = { 1048576, 131072, 131072, 131072, 131072, 524288, 524288 };
  int cum = 0;
  for (int i = 0; i < 7; ++i) { cs.src[i] = srcs[i]; cs.dst[i] = dsts[i]; cs.cum[i] = cum; cum += n8s[i]; }
  cs.cum[7] = cum;
  cast_multi<<<dim3((cum + 255) / 256), dim3(256), 0, stream>>>(cs);

  // QKV = x @ Wqkv^T  [8192 x 3072]  (256x128 tiles, 768 blocks = 3 full rounds)
  gemm128n<0><<<dim3(768), 512, 0, stream>>>(xb, wqkv, nullptr, qkv, nullptr, nullptr, vtb, 8192, 3072, 1024, 24);
  // causal attention -> z [8192 x 1024]
  attn_kernel<<<dim3(1024), 256, 0, stream>>>(qkv, vtb, zb);
  // x1 = x + z @ W_O^T   (256x128, 256 blocks)
  gemm128n<1><<<dim3(256), 512, 0, stream>>>(zb, wo, x1f, x1b, x, nullptr, nullptr, 8192, 1024, 1024, 8);
  // h = gelu(x1 @ W_in^T + b_in)  (256^2, 512 blocks = 2 full rounds)
  gemm256<2><<<dim3(512), 512, 0, stream>>>(x1b, win, nullptr, hb, nullptr, b_in, 8192, 4096, 1024, 16);
  // out = x1 + h @ W_out^T + b_out  (256x128, K=4096, 256 blocks)
  gemm128n<3><<<dim3(256), 512, 0, stream>>>(hb, wout, out, nullptr, x1f, b_out, nullptr, 8192, 1024, 4096, 8);
}